// Round 6
// baseline (774.349 us; speedup 1.0000x reference)
//
#include <hip/hip_runtime.h>

#define NEG_SLOPE 0.2f

// ---------------------------------------------------------------- CSR build
__global__ void zero_int_kernel(int* __restrict__ p, int n) {
  int i = blockIdx.x * blockDim.x + threadIdx.x;
  if (i < n) p[i] = 0;
}

__global__ void count_kernel(const int* __restrict__ ei, int E, int N,
                             int* __restrict__ cnt) {
  int e = blockIdx.x * blockDim.x + threadIdx.x;
  int tot = E + N;
  if (e >= tot) return;
  int dst = (e < E) ? ei[E + e] : (e - E);
  atomicAdd(&cnt[dst], 1);
}

// 1024 threads, one block. Per-thread serial chunk + shuffle block-scan.
__global__ __launch_bounds__(1024) void scan_kernel(const int* __restrict__ cnt,
                                                    int* __restrict__ row_ptr,
                                                    int* __restrict__ cursor,
                                                    int N) {
  int t = threadIdx.x;
  int CH = (N + 1023) >> 10;
  int b = t * CH; if (b > N) b = N;
  int e = b + CH; if (e > N) e = N;
  int sum = 0;
  for (int i = b; i < e; ++i) sum += cnt[i];
  int lane = t & 63, wid = t >> 6;
  int v = sum;
#pragma unroll
  for (int off = 1; off < 64; off <<= 1) {
    int u = __shfl_up(v, off, 64);
    if (lane >= off) v += u;
  }
  __shared__ int wsum[16];
  __shared__ int wpre[16];
  if (lane == 63) wsum[wid] = v;
  __syncthreads();
  if (t < 16) {
    int wv = wsum[t];
#pragma unroll
    for (int off = 1; off < 16; off <<= 1) {
      int u = __shfl_up(wv, off, 16);
      if (t >= off) wv += u;
    }
    wpre[t] = wv - wsum[t];
  }
  __syncthreads();
  int run = wpre[wid] + (v - sum);
  for (int i = b; i < e; ++i) {
    int c = cnt[i];
    row_ptr[i] = run;
    cursor[i] = run;
    run += c;
  }
  if (t == 1023) row_ptr[N] = run;
}

__global__ void fill_kernel(const int* __restrict__ ei, int E, int N,
                            int* __restrict__ cursor, int* __restrict__ col_src) {
  int e = blockIdx.x * blockDim.x + threadIdx.x;
  int tot = E + N;
  if (e >= tot) return;
  int src, dst;
  if (e < E) { src = ei[e]; dst = ei[E + e]; } else { src = e - E; dst = e - E; }
  int pos = atomicAdd(&cursor[dst], 1);
  col_src[pos] = src;
}

// ---------------------------------------------------------------- SGEMM fp32
// Y[M,N] = X[M,K] @ W[K,N].  256 threads, BK=16.  (round-2 proven: 117 us)
template <int BM, int BN>
__global__ __launch_bounds__(256) void sgemm_kernel(const float* __restrict__ X,
                                                    const float* __restrict__ W,
                                                    float* __restrict__ Y,
                                                    int M, int N, int K) {
  constexpr int BK = 16;
  constexpr int LDA = BM + 4;
  constexpr int HM = BM / 2;
  constexpr int JH = (BN == 128) ? 2 : 1;
  constexpr int HN = BN / 2;
  __shared__ float As[BK][LDA];
  __shared__ float Bs[BK][BN];
  int tid = threadIdx.x;
  int br = blockIdx.y * BM, bc = blockIdx.x * BN;
  int trow = tid >> 4, tcol = tid & 15;
  float acc[2][JH][4][4] = {};
  constexpr int nA4 = BM * BK / 1024;
  constexpr int nB4 = BK * BN / 1024;
  for (int k0 = 0; k0 < K; k0 += BK) {
#pragma unroll
    for (int i = 0; i < nA4; ++i) {
      int f = tid + i * 256;
      int row = f >> 2;
      int kq = (f & 3) * 4;
      int gm = br + row;
      float4 v = make_float4(0.f, 0.f, 0.f, 0.f);
      if (gm < M) v = *(const float4*)&X[(size_t)gm * K + k0 + kq];
      As[kq + 0][row] = v.x; As[kq + 1][row] = v.y;
      As[kq + 2][row] = v.z; As[kq + 3][row] = v.w;
    }
#pragma unroll
    for (int i = 0; i < nB4; ++i) {
      int f = tid + i * 256;
      int kk = f / (BN / 4);
      int nq = (f % (BN / 4)) * 4;
      *(float4*)&Bs[kk][nq] = *(const float4*)&W[(size_t)(k0 + kk) * N + bc + nq];
    }
    __syncthreads();
#pragma unroll
    for (int kk = 0; kk < BK; ++kk) {
      float ar[2][4], brg[JH][4];
      *(float4*)&ar[0][0] = *(const float4*)&As[kk][trow * 4];
      *(float4*)&ar[1][0] = *(const float4*)&As[kk][trow * 4 + HM];
      *(float4*)&brg[0][0] = *(const float4*)&Bs[kk][tcol * 4];
      if constexpr (JH == 2)
        *(float4*)&brg[1][0] = *(const float4*)&Bs[kk][tcol * 4 + HN];
#pragma unroll
      for (int ih = 0; ih < 2; ++ih)
#pragma unroll
        for (int jh = 0; jh < JH; ++jh)
#pragma unroll
          for (int i = 0; i < 4; ++i)
#pragma unroll
            for (int j = 0; j < 4; ++j)
              acc[ih][jh][i][j] += ar[ih][i] * brg[jh][j];
    }
    __syncthreads();
  }
#pragma unroll
  for (int ih = 0; ih < 2; ++ih)
#pragma unroll
    for (int i = 0; i < 4; ++i) {
      int gm = br + ih * HM + trow * 4 + i;
      if (gm >= M) continue;
#pragma unroll
      for (int jh = 0; jh < JH; ++jh) {
        float4 o = make_float4(acc[ih][jh][i][0], acc[ih][jh][i][1],
                               acc[ih][jh][i][2], acc[ih][jh][i][3]);
        int gn = bc + (JH == 2 ? jh * HN : 0) + tcol * 4;
        *(float4*)&Y[(size_t)gm * N + gn] = o;
      }
    }
}

// ------------------------------------------------- per-node alpha_s/alpha_d
template <int H, int C>
__global__ void alpha_kernel(const float* __restrict__ h,
                             const float* __restrict__ a_s,
                             const float* __restrict__ a_d,
                             float* __restrict__ out_s,
                             float* __restrict__ out_d, int N) {
  constexpr int HC = H * C;
  constexpr int PER = HC / 64;
  constexpr int SEG = C / PER;
  int lane = threadIdx.x & 63;
  int node = (blockIdx.x * blockDim.x + threadIdx.x) >> 6;
  if (node >= N) return;
  int cbase = lane * PER;
  const float* row = h + (size_t)node * HC + cbase;
  float ss, dd;
  if constexpr (PER == 4) {
    float4 v = *(const float4*)row;
    float4 s4 = *(const float4*)(a_s + cbase);
    float4 d4 = *(const float4*)(a_d + cbase);
    ss = v.x * s4.x + v.y * s4.y + v.z * s4.z + v.w * s4.w;
    dd = v.x * d4.x + v.y * d4.y + v.z * d4.z + v.w * d4.w;
  } else {
    float v = row[0];
    ss = v * a_s[cbase];
    dd = v * a_d[cbase];
  }
#pragma unroll
  for (int off = SEG >> 1; off >= 1; off >>= 1) {
    ss += __shfl_xor(ss, off, 64);
    dd += __shfl_xor(dd, off, 64);
  }
  if ((lane % SEG) == 0) {
    int head = lane / SEG;
    out_s[(size_t)node * H + head] = ss;
    out_d[(size_t)node * H + head] = dd;
  }
}

// --------------------------- aggregation, H=4: one WAVE per (node, head)
// 4x the waves of wave-per-node -> 4x outstanding gathers device-wide.
// Each edge gather = 64 lanes x 1 float (256B coalesced).
// Edges processed in padded groups of 8 (zero-weight lanes contribute 0).
template <bool RELU>
__global__ void aggregate4_kernel(const float* __restrict__ h,
                                  const float* __restrict__ as_,
                                  const float* __restrict__ ad_,
                                  const int* __restrict__ row_ptr,
                                  const int* __restrict__ col_src,
                                  const float* __restrict__ bias,
                                  float* __restrict__ out, int N) {
  int node = blockIdx.x;            // one block per node
  int head = threadIdx.x >> 6;      // wave id = head
  int lane = threadIdx.x & 63;
  int beg = row_ptr[node], end = row_ptr[node + 1];
  int deg = end - beg;
  float inv_deg = 1.f / (float)deg;
  float adv = ad_[(size_t)node * 4 + head];
  const float* hb = h + head * 64 + lane;   // + s*256 per edge
  float facc = 0.f;

  if (deg <= 64) {
    float q = 0.f; int s_w = 0;
    if (lane < deg) {
      s_w = col_src[beg + lane];
      float e = as_[(size_t)s_w * 4 + head] + adv;
      e = (e > 0.f) ? e : NEG_SLOPE * e;
      q = __expf(e);
    }
    float dn = q;
#pragma unroll
    for (int off = 32; off >= 1; off >>= 1) dn += __shfl_xor(dn, off, 64);
    float qs = q * (1.f / dn) * inv_deg;   // 0 for padded lanes
    int deg8 = (deg + 7) & ~7;             // padded lanes: s_w=0, qs=0
    for (int i = 0; i < deg8; i += 8) {
      int s0 = __shfl(s_w, i + 0, 64); float w0 = __shfl(qs, i + 0, 64);
      int s1 = __shfl(s_w, i + 1, 64); float w1 = __shfl(qs, i + 1, 64);
      int s2 = __shfl(s_w, i + 2, 64); float w2 = __shfl(qs, i + 2, 64);
      int s3 = __shfl(s_w, i + 3, 64); float w3 = __shfl(qs, i + 3, 64);
      int s4 = __shfl(s_w, i + 4, 64); float w4 = __shfl(qs, i + 4, 64);
      int s5 = __shfl(s_w, i + 5, 64); float w5 = __shfl(qs, i + 5, 64);
      int s6 = __shfl(s_w, i + 6, 64); float w6 = __shfl(qs, i + 6, 64);
      int s7 = __shfl(s_w, i + 7, 64); float w7 = __shfl(qs, i + 7, 64);
      float v0 = hb[(size_t)s0 * 256];
      float v1 = hb[(size_t)s1 * 256];
      float v2 = hb[(size_t)s2 * 256];
      float v3 = hb[(size_t)s3 * 256];
      float v4 = hb[(size_t)s4 * 256];
      float v5 = hb[(size_t)s5 * 256];
      float v6 = hb[(size_t)s6 * 256];
      float v7 = hb[(size_t)s7 * 256];
      facc += v0 * w0 + v1 * w1 + v2 * w2 + v3 * w3;
      facc += v4 * w4 + v5 * w5 + v6 * w6 + v7 * w7;
    }
  } else {
    // deg > 64 fallback: two-pass, chunked by 64
    float dn = 0.f;
    for (int i = beg + lane; i < end; i += 64) {
      int s = col_src[i];
      float e = as_[(size_t)s * 4 + head] + adv;
      e = (e > 0.f) ? e : NEG_SLOPE * e;
      dn += __expf(e);
    }
#pragma unroll
    for (int off = 32; off >= 1; off >>= 1) dn += __shfl_xor(dn, off, 64);
    float scale = (1.f / dn) * inv_deg;
    for (int base = beg; base < end; base += 64) {
      int i2 = base + lane;
      float q2 = 0.f; int s2r = 0;
      if (i2 < end) {
        s2r = col_src[i2];
        float e = as_[(size_t)s2r * 4 + head] + adv;
        e = (e > 0.f) ? e : NEG_SLOPE * e;
        q2 = __expf(e) * scale;
      }
      int cnt = end - base; if (cnt > 64) cnt = 64;
      int cnt8 = (cnt + 7) & ~7;
      for (int j = 0; j < cnt8; j += 8) {
        int s0 = __shfl(s2r, j + 0, 64); float w0 = __shfl(q2, j + 0, 64);
        int s1 = __shfl(s2r, j + 1, 64); float w1 = __shfl(q2, j + 1, 64);
        int s2 = __shfl(s2r, j + 2, 64); float w2 = __shfl(q2, j + 2, 64);
        int s3 = __shfl(s2r, j + 3, 64); float w3 = __shfl(q2, j + 3, 64);
        int s4 = __shfl(s2r, j + 4, 64); float w4 = __shfl(q2, j + 4, 64);
        int s5 = __shfl(s2r, j + 5, 64); float w5 = __shfl(q2, j + 5, 64);
        int s6 = __shfl(s2r, j + 6, 64); float w6 = __shfl(q2, j + 6, 64);
        int s7 = __shfl(s2r, j + 7, 64); float w7 = __shfl(q2, j + 7, 64);
        float v0 = hb[(size_t)s0 * 256];
        float v1 = hb[(size_t)s1 * 256];
        float v2 = hb[(size_t)s2 * 256];
        float v3 = hb[(size_t)s3 * 256];
        float v4 = hb[(size_t)s4 * 256];
        float v5 = hb[(size_t)s5 * 256];
        float v6 = hb[(size_t)s6 * 256];
        float v7 = hb[(size_t)s7 * 256];
        facc += v0 * w0 + v1 * w1 + v2 * w2 + v3 * w3;
        facc += v4 * w4 + v5 * w5 + v6 * w6 + v7 * w7;
      }
    }
  }

  float vout = facc + bias[head * 64 + lane];
  if (RELU) vout = fmaxf(vout, 0.f);
  out[(size_t)node * 256 + head * 64 + lane] = vout;
}

// --------------------------- aggregation, H=1 (layer 2): one wave per node
template <bool RELU>
__global__ void aggregate1_kernel(const float* __restrict__ h,
                                  const float* __restrict__ as_,
                                  const float* __restrict__ ad_,
                                  const int* __restrict__ row_ptr,
                                  const int* __restrict__ col_src,
                                  const float* __restrict__ bias,
                                  float* __restrict__ out, int N) {
  int lane = threadIdx.x & 63;
  int node = (blockIdx.x * blockDim.x + threadIdx.x) >> 6;
  if (node >= N) return;
  int beg = row_ptr[node], end = row_ptr[node + 1];
  int deg = end - beg;
  float inv_deg = 1.f / (float)deg;
  float adv = ad_[node];
  const float* hb = h + lane;
  float facc = 0.f;

  if (deg <= 64) {
    float q = 0.f; int s_w = 0;
    if (lane < deg) {
      s_w = col_src[beg + lane];
      float e = as_[s_w] + adv;
      e = (e > 0.f) ? e : NEG_SLOPE * e;
      q = __expf(e);
    }
    float dn = q;
#pragma unroll
    for (int off = 32; off >= 1; off >>= 1) dn += __shfl_xor(dn, off, 64);
    float qs = q * (1.f / dn) * inv_deg;
    int deg8 = (deg + 7) & ~7;
    for (int i = 0; i < deg8; i += 8) {
      int s0 = __shfl(s_w, i + 0, 64); float w0 = __shfl(qs, i + 0, 64);
      int s1 = __shfl(s_w, i + 1, 64); float w1 = __shfl(qs, i + 1, 64);
      int s2 = __shfl(s_w, i + 2, 64); float w2 = __shfl(qs, i + 2, 64);
      int s3 = __shfl(s_w, i + 3, 64); float w3 = __shfl(qs, i + 3, 64);
      int s4 = __shfl(s_w, i + 4, 64); float w4 = __shfl(qs, i + 4, 64);
      int s5 = __shfl(s_w, i + 5, 64); float w5 = __shfl(qs, i + 5, 64);
      int s6 = __shfl(s_w, i + 6, 64); float w6 = __shfl(qs, i + 6, 64);
      int s7 = __shfl(s_w, i + 7, 64); float w7 = __shfl(qs, i + 7, 64);
      float v0 = hb[(size_t)s0 * 64];
      float v1 = hb[(size_t)s1 * 64];
      float v2 = hb[(size_t)s2 * 64];
      float v3 = hb[(size_t)s3 * 64];
      float v4 = hb[(size_t)s4 * 64];
      float v5 = hb[(size_t)s5 * 64];
      float v6 = hb[(size_t)s6 * 64];
      float v7 = hb[(size_t)s7 * 64];
      facc += v0 * w0 + v1 * w1 + v2 * w2 + v3 * w3;
      facc += v4 * w4 + v5 * w5 + v6 * w6 + v7 * w7;
    }
  } else {
    float dn = 0.f;
    for (int i = beg + lane; i < end; i += 64) {
      int s = col_src[i];
      float e = as_[s] + adv;
      e = (e > 0.f) ? e : NEG_SLOPE * e;
      dn += __expf(e);
    }
#pragma unroll
    for (int off = 32; off >= 1; off >>= 1) dn += __shfl_xor(dn, off, 64);
    float scale = (1.f / dn) * inv_deg;
    for (int base = beg; base < end; base += 64) {
      int i2 = base + lane;
      float q2 = 0.f; int s2r = 0;
      if (i2 < end) {
        s2r = col_src[i2];
        float e = as_[s2r] + adv;
        e = (e > 0.f) ? e : NEG_SLOPE * e;
        q2 = __expf(e) * scale;
      }
      int cnt = end - base; if (cnt > 64) cnt = 64;
      int cnt8 = (cnt + 7) & ~7;
      for (int j = 0; j < cnt8; j += 8) {
        int s0 = __shfl(s2r, j + 0, 64); float w0 = __shfl(q2, j + 0, 64);
        int s1 = __shfl(s2r, j + 1, 64); float w1 = __shfl(q2, j + 1, 64);
        int s2 = __shfl(s2r, j + 2, 64); float w2 = __shfl(q2, j + 2, 64);
        int s3 = __shfl(s2r, j + 3, 64); float w3 = __shfl(q2, j + 3, 64);
        int s4 = __shfl(s2r, j + 4, 64); float w4 = __shfl(q2, j + 4, 64);
        int s5 = __shfl(s2r, j + 5, 64); float w5 = __shfl(q2, j + 5, 64);
        int s6 = __shfl(s2r, j + 6, 64); float w6 = __shfl(q2, j + 6, 64);
        int s7 = __shfl(s2r, j + 7, 64); float w7 = __shfl(q2, j + 7, 64);
        float v0 = hb[(size_t)s0 * 64];
        float v1 = hb[(size_t)s1 * 64];
        float v2 = hb[(size_t)s2 * 64];
        float v3 = hb[(size_t)s3 * 64];
        float v4 = hb[(size_t)s4 * 64];
        float v5 = hb[(size_t)s5 * 64];
        float v6 = hb[(size_t)s6 * 64];
        float v7 = hb[(size_t)s7 * 64];
        facc += v0 * w0 + v1 * w1 + v2 * w2 + v3 * w3;
        facc += v4 * w4 + v5 * w5 + v6 * w6 + v7 * w7;
      }
    }
  }

  float vout = facc + bias[lane];
  if (RELU) vout = fmaxf(vout, 0.f);
  out[(size_t)node * 64 + lane] = vout;
}

// ---------------------------------------------------------------- launcher
extern "C" void kernel_launch(void* const* d_in, const int* in_sizes, int n_in,
                              void* d_out, int out_size, void* d_ws, size_t ws_size,
                              hipStream_t stream) {
  const float* x   = (const float*)d_in[0];
  const int*   ei  = (const int*)d_in[1];
  const float* W0  = (const float*)d_in[2];
  const float* a0s = (const float*)d_in[3];
  const float* a0d = (const float*)d_in[4];
  const float* b0  = (const float*)d_in[5];
  const float* W1  = (const float*)d_in[6];
  const float* a1s = (const float*)d_in[7];
  const float* a1d = (const float*)d_in[8];
  const float* b1  = (const float*)d_in[9];
  const float* W2  = (const float*)d_in[10];
  const float* a2s = (const float*)d_in[11];
  const float* a2d = (const float*)d_in[12];
  const float* b2  = (const float*)d_in[13];

  const int IN = 256;
  const int N = in_sizes[0] / IN;       // 50000
  const int E = in_sizes[1] / 2;        // 600000
  const int Etot = E + N;

  char* ws = (char*)d_ws;
  size_t off = 0;
  auto alloc = [&](size_t bytes) {
    void* p = ws + off;
    off += (bytes + 255) & ~(size_t)255;
    return p;
  };
  float* A       = (float*)alloc((size_t)N * 256 * 4);
  float* Bbuf    = (float*)alloc((size_t)N * 256 * 4);
  float* as_buf  = (float*)alloc((size_t)N * 4 * 4);
  float* ad_buf  = (float*)alloc((size_t)N * 4 * 4);
  int*   row_ptr = (int*)alloc((size_t)(N + 1) * 4);
  int*   cursor  = (int*)alloc((size_t)N * 4);
  int*   cnt     = (int*)alloc((size_t)N * 4);
  int*   col_src = (int*)alloc((size_t)Etot * 4);

  // ---- CSR build ----
  zero_int_kernel<<<(N + 255) / 256, 256, 0, stream>>>(cnt, N);
  count_kernel<<<(Etot + 255) / 256, 256, 0, stream>>>(ei, E, N, cnt);
  scan_kernel<<<1, 1024, 0, stream>>>(cnt, row_ptr, cursor, N);
  fill_kernel<<<(Etot + 255) / 256, 256, 0, stream>>>(ei, E, N, cursor, col_src);

  dim3 g0(256 / 128, (N + 127) / 128);  // 2 x 391
  dim3 g2(64 / 64, (N + 127) / 128);    // 1 x 391
  int node_blocks = (N + 3) / 4;

  // ---- layer 0 ----
  sgemm_kernel<128, 128><<<g0, 256, 0, stream>>>(x, W0, A, N, 256, 256);
  alpha_kernel<4, 64><<<node_blocks, 256, 0, stream>>>(A, a0s, a0d, as_buf, ad_buf, N);
  aggregate4_kernel<true><<<N, 256, 0, stream>>>(
      A, as_buf, ad_buf, row_ptr, col_src, b0, Bbuf, N);

  // ---- layer 1 ----
  sgemm_kernel<128, 128><<<g0, 256, 0, stream>>>(Bbuf, W1, A, N, 256, 256);
  alpha_kernel<4, 64><<<node_blocks, 256, 0, stream>>>(A, a1s, a1d, as_buf, ad_buf, N);
  aggregate4_kernel<true><<<N, 256, 0, stream>>>(
      A, as_buf, ad_buf, row_ptr, col_src, b1, Bbuf, N);

  // ---- layer 2 ----
  sgemm_kernel<128, 64><<<g2, 256, 0, stream>>>(Bbuf, W2, A, N, 64, 256);
  alpha_kernel<1, 64><<<node_blocks, 256, 0, stream>>>(A, a2s, a2d, as_buf, ad_buf, N);
  aggregate1_kernel<false><<<node_blocks, 256, 0, stream>>>(
      A, as_buf, ad_buf, row_ptr, col_src, b2, (float*)d_out, N);
}

// Round 7
// 675.921 us; speedup vs baseline: 1.1456x; 1.1456x over previous
//
#include <hip/hip_runtime.h>
#include <hip/hip_fp16.h>

#define NEG_SLOPE 0.2f

// ---------------------------------------------------------------- CSR build
__global__ void zero_int_kernel(int* __restrict__ p, int n) {
  int i = blockIdx.x * blockDim.x + threadIdx.x;
  if (i < n) p[i] = 0;
}

__global__ void count_kernel(const int* __restrict__ ei, int E, int N,
                             int* __restrict__ cnt) {
  int e = blockIdx.x * blockDim.x + threadIdx.x;
  int tot = E + N;
  if (e >= tot) return;
  int dst = (e < E) ? ei[E + e] : (e - E);
  atomicAdd(&cnt[dst], 1);
}

// 1024 threads, one block. Per-thread serial chunk + shuffle block-scan.
__global__ __launch_bounds__(1024) void scan_kernel(const int* __restrict__ cnt,
                                                    int* __restrict__ row_ptr,
                                                    int* __restrict__ cursor,
                                                    int N) {
  int t = threadIdx.x;
  int CH = (N + 1023) >> 10;
  int b = t * CH; if (b > N) b = N;
  int e = b + CH; if (e > N) e = N;
  int sum = 0;
  for (int i = b; i < e; ++i) sum += cnt[i];
  int lane = t & 63, wid = t >> 6;
  int v = sum;
#pragma unroll
  for (int off = 1; off < 64; off <<= 1) {
    int u = __shfl_up(v, off, 64);
    if (lane >= off) v += u;
  }
  __shared__ int wsum[16];
  __shared__ int wpre[16];
  if (lane == 63) wsum[wid] = v;
  __syncthreads();
  if (t < 16) {
    int wv = wsum[t];
#pragma unroll
    for (int off = 1; off < 16; off <<= 1) {
      int u = __shfl_up(wv, off, 16);
      if (t >= off) wv += u;
    }
    wpre[t] = wv - wsum[t];
  }
  __syncthreads();
  int run = wpre[wid] + (v - sum);
  for (int i = b; i < e; ++i) {
    int c = cnt[i];
    row_ptr[i] = run;
    cursor[i] = run;
    run += c;
  }
  if (t == 1023) row_ptr[N] = run;
}

__global__ void fill_kernel(const int* __restrict__ ei, int E, int N,
                            int* __restrict__ cursor, int* __restrict__ col_src) {
  int e = blockIdx.x * blockDim.x + threadIdx.x;
  int tot = E + N;
  if (e >= tot) return;
  int src, dst;
  if (e < E) { src = ei[e]; dst = ei[E + e]; } else { src = e - E; dst = e - E; }
  int pos = atomicAdd(&cursor[dst], 1);
  col_src[pos] = src;
}

// ---------------------------------------------------------------- SGEMM fp32
// Y[M,N] = X[M,K] @ W[K,N]; also writes fp16 copy Y16 (gather path).
template <int BM, int BN>
__global__ __launch_bounds__(256) void sgemm_kernel(const float* __restrict__ X,
                                                    const float* __restrict__ W,
                                                    float* __restrict__ Y,
                                                    __half* __restrict__ Y16,
                                                    int M, int N, int K) {
  constexpr int BK = 16;
  constexpr int LDA = BM + 4;
  constexpr int HM = BM / 2;
  constexpr int JH = (BN == 128) ? 2 : 1;
  constexpr int HN = BN / 2;
  __shared__ float As[BK][LDA];
  __shared__ float Bs[BK][BN];
  int tid = threadIdx.x;
  int br = blockIdx.y * BM, bc = blockIdx.x * BN;
  int trow = tid >> 4, tcol = tid & 15;
  float acc[2][JH][4][4] = {};
  constexpr int nA4 = BM * BK / 1024;
  constexpr int nB4 = BK * BN / 1024;
  for (int k0 = 0; k0 < K; k0 += BK) {
#pragma unroll
    for (int i = 0; i < nA4; ++i) {
      int f = tid + i * 256;
      int row = f >> 2;
      int kq = (f & 3) * 4;
      int gm = br + row;
      float4 v = make_float4(0.f, 0.f, 0.f, 0.f);
      if (gm < M) v = *(const float4*)&X[(size_t)gm * K + k0 + kq];
      As[kq + 0][row] = v.x; As[kq + 1][row] = v.y;
      As[kq + 2][row] = v.z; As[kq + 3][row] = v.w;
    }
#pragma unroll
    for (int i = 0; i < nB4; ++i) {
      int f = tid + i * 256;
      int kk = f / (BN / 4);
      int nq = (f % (BN / 4)) * 4;
      *(float4*)&Bs[kk][nq] = *(const float4*)&W[(size_t)(k0 + kk) * N + bc + nq];
    }
    __syncthreads();
#pragma unroll
    for (int kk = 0; kk < BK; ++kk) {
      float ar[2][4], brg[JH][4];
      *(float4*)&ar[0][0] = *(const float4*)&As[kk][trow * 4];
      *(float4*)&ar[1][0] = *(const float4*)&As[kk][trow * 4 + HM];
      *(float4*)&brg[0][0] = *(const float4*)&Bs[kk][tcol * 4];
      if constexpr (JH == 2)
        *(float4*)&brg[1][0] = *(const float4*)&Bs[kk][tcol * 4 + HN];
#pragma unroll
      for (int ih = 0; ih < 2; ++ih)
#pragma unroll
        for (int jh = 0; jh < JH; ++jh)
#pragma unroll
          for (int i = 0; i < 4; ++i)
#pragma unroll
            for (int j = 0; j < 4; ++j)
              acc[ih][jh][i][j] += ar[ih][i] * brg[jh][j];
    }
    __syncthreads();
  }
#pragma unroll
  for (int ih = 0; ih < 2; ++ih)
#pragma unroll
    for (int i = 0; i < 4; ++i) {
      int gm = br + ih * HM + trow * 4 + i;
      if (gm >= M) continue;
#pragma unroll
      for (int jh = 0; jh < JH; ++jh) {
        float4 o = make_float4(acc[ih][jh][i][0], acc[ih][jh][i][1],
                               acc[ih][jh][i][2], acc[ih][jh][i][3]);
        int gn = bc + (JH == 2 ? jh * HN : 0) + tcol * 4;
        *(float4*)&Y[(size_t)gm * N + gn] = o;
        union { __half2 h2[2]; float2 f2; } u;
        u.h2[0] = __floats2half2_rn(o.x, o.y);
        u.h2[1] = __floats2half2_rn(o.z, o.w);
        *(float2*)&Y16[(size_t)gm * N + gn] = u.f2;
      }
    }
}

// ------------------------------------------------- per-node alpha_s/alpha_d
template <int H, int C>
__global__ void alpha_kernel(const float* __restrict__ h,
                             const float* __restrict__ a_s,
                             const float* __restrict__ a_d,
                             float* __restrict__ out_s,
                             float* __restrict__ out_d, int N) {
  constexpr int HC = H * C;
  constexpr int PER = HC / 64;
  constexpr int SEG = C / PER;
  int lane = threadIdx.x & 63;
  int node = (blockIdx.x * blockDim.x + threadIdx.x) >> 6;
  if (node >= N) return;
  int cbase = lane * PER;
  const float* row = h + (size_t)node * HC + cbase;
  float ss, dd;
  if constexpr (PER == 4) {
    float4 v = *(const float4*)row;
    float4 s4 = *(const float4*)(a_s + cbase);
    float4 d4 = *(const float4*)(a_d + cbase);
    ss = v.x * s4.x + v.y * s4.y + v.z * s4.z + v.w * s4.w;
    dd = v.x * d4.x + v.y * d4.y + v.z * d4.z + v.w * d4.w;
  } else {
    float v = row[0];
    ss = v * a_s[cbase];
    dd = v * a_d[cbase];
  }
#pragma unroll
  for (int off = SEG >> 1; off >= 1; off >>= 1) {
    ss += __shfl_xor(ss, off, 64);
    dd += __shfl_xor(dd, off, 64);
  }
  if ((lane % SEG) == 0) {
    int head = lane / SEG;
    out_s[(size_t)node * H + head] = ss;
    out_d[(size_t)node * H + head] = dd;
  }
}

// helper: gather 4 consecutive halfs (8B) and fma into facc with weight w
__device__ __forceinline__ void fma_h4(const __half* p, float w, float* facc) {
  union { float2 f2; __half2 h2[2]; } c;
  c.f2 = *(const float2*)p;
  float2 lo = __half22float2(c.h2[0]);
  float2 hi = __half22float2(c.h2[1]);
  facc[0] += lo.x * w; facc[1] += lo.y * w;
  facc[2] += hi.x * w; facc[3] += hi.y * w;
}

// ------------------------------- segment softmax + mean-aggregate + bias(+relu)
// One wave per dst node; gathers fp16 h rows (half traffic of fp32).
// NOTE: __shfl(expr, i) evaluates expr on the SOURCE lane — head-dependent
// select must happen AFTER the shuffle.
template <bool RELU>
__global__ void aggregate4_kernel(const __half* __restrict__ h16,
                                  const float* __restrict__ as_,
                                  const float* __restrict__ ad_,
                                  const int* __restrict__ row_ptr,
                                  const int* __restrict__ col_src,
                                  const float* __restrict__ bias,
                                  float* __restrict__ out, int N) {
  int lane = threadIdx.x & 63;
  int node = (blockIdx.x * blockDim.x + threadIdx.x) >> 6;
  if (node >= N) return;
  int beg = row_ptr[node], end = row_ptr[node + 1];
  int deg = end - beg;
  float inv_deg = 1.f / (float)deg;
  int myhead = lane >> 4;
  float facc[4] = {};
  float4 adv4 = *(const float4*)(ad_ + (size_t)node * 4);
  const __half* hl = h16 + lane * 4;   // + s*256 per edge

  if (deg <= 16) {
    // lane = head_w*16 + e_w holds weight of edge e_w for head head_w;
    // consumer reads from its own head group -> single shfl pair per edge.
    int head_w = lane >> 4, e_w = lane & 15;
    float q = 0.f; int s_w = 0;
    if (e_w < deg) {
      s_w = col_src[beg + e_w];
      float4 a4 = *(const float4*)(as_ + (size_t)s_w * 4);
      float av = head_w == 0 ? a4.x : head_w == 1 ? a4.y : head_w == 2 ? a4.z : a4.w;
      float dv = head_w == 0 ? adv4.x : head_w == 1 ? adv4.y : head_w == 2 ? adv4.z : adv4.w;
      float e = av + dv;
      e = (e > 0.f) ? e : NEG_SLOPE * e;
      q = __expf(e);
    }
    float dn = q;
    dn += __shfl_xor(dn, 1, 64);
    dn += __shfl_xor(dn, 2, 64);
    dn += __shfl_xor(dn, 4, 64);
    dn += __shfl_xor(dn, 8, 64);
    float qs = q * (1.f / dn) * inv_deg;
    int base = myhead << 4;
    int i = 0;
    for (; i + 4 <= deg; i += 4) {
      int s0 = __shfl(s_w, base + i + 0, 64); float w0 = __shfl(qs, base + i + 0, 64);
      int s1 = __shfl(s_w, base + i + 1, 64); float w1 = __shfl(qs, base + i + 1, 64);
      int s2 = __shfl(s_w, base + i + 2, 64); float w2 = __shfl(qs, base + i + 2, 64);
      int s3 = __shfl(s_w, base + i + 3, 64); float w3 = __shfl(qs, base + i + 3, 64);
      fma_h4(hl + (size_t)s0 * 256, w0, facc);
      fma_h4(hl + (size_t)s1 * 256, w1, facc);
      fma_h4(hl + (size_t)s2 * 256, w2, facc);
      fma_h4(hl + (size_t)s3 * 256, w3, facc);
    }
    for (; i < deg; ++i) {
      int srcn = __shfl(s_w, base + i, 64);
      float w = __shfl(qs, base + i, 64);
      fma_h4(hl + (size_t)srcn * 256, w, facc);
    }
  } else if (deg <= 64) {
    float p0 = 0.f, p1 = 0.f, p2 = 0.f, p3 = 0.f; int s_w = 0;
    if (lane < deg) {
      s_w = col_src[beg + lane];
      float4 a4 = *(const float4*)(as_ + (size_t)s_w * 4);
      float e0 = a4.x + adv4.x; e0 = e0 > 0.f ? e0 : NEG_SLOPE * e0; p0 = __expf(e0);
      float e1 = a4.y + adv4.y; e1 = e1 > 0.f ? e1 : NEG_SLOPE * e1; p1 = __expf(e1);
      float e2 = a4.z + adv4.z; e2 = e2 > 0.f ? e2 : NEG_SLOPE * e2; p2 = __expf(e2);
      float e3 = a4.w + adv4.w; e3 = e3 > 0.f ? e3 : NEG_SLOPE * e3; p3 = __expf(e3);
    }
    float d0 = p0, d1 = p1, d2 = p2, d3 = p3;
#pragma unroll
    for (int off = 32; off >= 1; off >>= 1) {
      d0 += __shfl_xor(d0, off, 64);
      d1 += __shfl_xor(d1, off, 64);
      d2 += __shfl_xor(d2, off, 64);
      d3 += __shfl_xor(d3, off, 64);
    }
    p0 *= (1.f / d0) * inv_deg;
    p1 *= (1.f / d1) * inv_deg;
    p2 *= (1.f / d2) * inv_deg;
    p3 *= (1.f / d3) * inv_deg;
    int i = 0;
    for (; i + 2 <= deg; i += 2) {
      int s0 = __shfl(s_w, i + 0, 64);
      int s1 = __shfl(s_w, i + 1, 64);
      float a00 = __shfl(p0, i + 0, 64), a01 = __shfl(p1, i + 0, 64);
      float a02 = __shfl(p2, i + 0, 64), a03 = __shfl(p3, i + 0, 64);
      float a10 = __shfl(p0, i + 1, 64), a11 = __shfl(p1, i + 1, 64);
      float a12 = __shfl(p2, i + 1, 64), a13 = __shfl(p3, i + 1, 64);
      float w0 = myhead == 0 ? a00 : myhead == 1 ? a01 : myhead == 2 ? a02 : a03;
      float w1 = myhead == 0 ? a10 : myhead == 1 ? a11 : myhead == 2 ? a12 : a13;
      fma_h4(hl + (size_t)s0 * 256, w0, facc);
      fma_h4(hl + (size_t)s1 * 256, w1, facc);
    }
    for (; i < deg; ++i) {
      int srcn = __shfl(s_w, i, 64);
      float b0 = __shfl(p0, i, 64), b1 = __shfl(p1, i, 64);
      float b2 = __shfl(p2, i, 64), b3 = __shfl(p3, i, 64);
      float w = myhead == 0 ? b0 : myhead == 1 ? b1 : myhead == 2 ? b2 : b3;
      fma_h4(hl + (size_t)srcn * 256, w, facc);
    }
  } else {
    // deg > 64: strided two-pass (rare)
    float dn0 = 0.f, dn1 = 0.f, dn2 = 0.f, dn3 = 0.f;
    for (int i = beg + lane; i < end; i += 64) {
      int s = col_src[i];
      float4 a4 = *(const float4*)(as_ + (size_t)s * 4);
      float e0 = a4.x + adv4.x; e0 = e0 > 0.f ? e0 : NEG_SLOPE * e0; dn0 += __expf(e0);
      float e1 = a4.y + adv4.y; e1 = e1 > 0.f ? e1 : NEG_SLOPE * e1; dn1 += __expf(e1);
      float e2 = a4.z + adv4.z; e2 = e2 > 0.f ? e2 : NEG_SLOPE * e2; dn2 += __expf(e2);
      float e3 = a4.w + adv4.w; e3 = e3 > 0.f ? e3 : NEG_SLOPE * e3; dn3 += __expf(e3);
    }
#pragma unroll
    for (int off = 32; off >= 1; off >>= 1) {
      dn0 += __shfl_xor(dn0, off, 64);
      dn1 += __shfl_xor(dn1, off, 64);
      dn2 += __shfl_xor(dn2, off, 64);
      dn3 += __shfl_xor(dn3, off, 64);
    }
    float adm = myhead == 0 ? adv4.x : myhead == 1 ? adv4.y : myhead == 2 ? adv4.z : adv4.w;
    float invdn = 1.f / (myhead == 0 ? dn0 : myhead == 1 ? dn1 : myhead == 2 ? dn2 : dn3);
    invdn *= inv_deg;
    for (int i = beg; i < end; ++i) {
      int s = col_src[i];
      float e = as_[(size_t)s * 4 + myhead] + adm;
      e = (e > 0.f) ? e : NEG_SLOPE * e;
      float w = __expf(e) * invdn;
      fma_h4(hl + (size_t)s * 256, w, facc);
    }
  }

  float* orow = out + (size_t)node * 256 + lane * 4;
#pragma unroll
  for (int p = 0; p < 4; ++p) {
    float v = facc[p] + bias[lane * 4 + p];
    if (RELU) v = fmaxf(v, 0.f);
    orow[p] = v;
  }
}

// --------------------------- aggregation, H=1 (layer 2): one wave per node
template <bool RELU>
__global__ void aggregate1_kernel(const __half* __restrict__ h16,
                                  const float* __restrict__ as_,
                                  const float* __restrict__ ad_,
                                  const int* __restrict__ row_ptr,
                                  const int* __restrict__ col_src,
                                  const float* __restrict__ bias,
                                  float* __restrict__ out, int N) {
  int lane = threadIdx.x & 63;
  int node = (blockIdx.x * blockDim.x + threadIdx.x) >> 6;
  if (node >= N) return;
  int beg = row_ptr[node], end = row_ptr[node + 1];
  int deg = end - beg;
  float inv_deg = 1.f / (float)deg;
  float adv = ad_[node];
  const __half* hb = h16 + lane;
  float facc = 0.f;

  if (deg <= 64) {
    float q = 0.f; int s_w = 0;
    if (lane < deg) {
      s_w = col_src[beg + lane];
      float e = as_[s_w] + adv;
      e = (e > 0.f) ? e : NEG_SLOPE * e;
      q = __expf(e);
    }
    float dn = q;
#pragma unroll
    for (int off = 32; off >= 1; off >>= 1) dn += __shfl_xor(dn, off, 64);
    float qs = q * (1.f / dn) * inv_deg;
    int deg8 = (deg + 7) & ~7;             // padded lanes: s_w=0, qs=0
    for (int i = 0; i < deg8; i += 8) {
      int s0 = __shfl(s_w, i + 0, 64); float w0 = __shfl(qs, i + 0, 64);
      int s1 = __shfl(s_w, i + 1, 64); float w1 = __shfl(qs, i + 1, 64);
      int s2 = __shfl(s_w, i + 2, 64); float w2 = __shfl(qs, i + 2, 64);
      int s3 = __shfl(s_w, i + 3, 64); float w3 = __shfl(qs, i + 3, 64);
      int s4 = __shfl(s_w, i + 4, 64); float w4 = __shfl(qs, i + 4, 64);
      int s5 = __shfl(s_w, i + 5, 64); float w5 = __shfl(qs, i + 5, 64);
      int s6 = __shfl(s_w, i + 6, 64); float w6 = __shfl(qs, i + 6, 64);
      int s7 = __shfl(s_w, i + 7, 64); float w7 = __shfl(qs, i + 7, 64);
      float v0 = __half2float(hb[(size_t)s0 * 64]);
      float v1 = __half2float(hb[(size_t)s1 * 64]);
      float v2 = __half2float(hb[(size_t)s2 * 64]);
      float v3 = __half2float(hb[(size_t)s3 * 64]);
      float v4 = __half2float(hb[(size_t)s4 * 64]);
      float v5 = __half2float(hb[(size_t)s5 * 64]);
      float v6 = __half2float(hb[(size_t)s6 * 64]);
      float v7 = __half2float(hb[(size_t)s7 * 64]);
      facc += v0 * w0 + v1 * w1 + v2 * w2 + v3 * w3;
      facc += v4 * w4 + v5 * w5 + v6 * w6 + v7 * w7;
    }
  } else {
    float dn = 0.f;
    for (int i = beg + lane; i < end; i += 64) {
      int s = col_src[i];
      float e = as_[s] + adv;
      e = (e > 0.f) ? e : NEG_SLOPE * e;
      dn += __expf(e);
    }
#pragma unroll
    for (int off = 32; off >= 1; off >>= 1) dn += __shfl_xor(dn, off, 64);
    float scale = (1.f / dn) * inv_deg;
    for (int base = beg; base < end; base += 64) {
      int i2 = base + lane;
      float q2 = 0.f; int s2r = 0;
      if (i2 < end) {
        s2r = col_src[i2];
        float e = as_[s2r] + adv;
        e = (e > 0.f) ? e : NEG_SLOPE * e;
        q2 = __expf(e) * scale;
      }
      int cnt = end - base; if (cnt > 64) cnt = 64;
      for (int j = 0; j < cnt; ++j) {
        int s = __shfl(s2r, j, 64);
        float w = __shfl(q2, j, 64);
        facc += __half2float(hb[(size_t)s * 64]) * w;
      }
    }
  }

  float vout = facc + bias[lane];
  if (RELU) vout = fmaxf(vout, 0.f);
  out[(size_t)node * 64 + lane] = vout;
}

// ---------------------------------------------------------------- launcher
extern "C" void kernel_launch(void* const* d_in, const int* in_sizes, int n_in,
                              void* d_out, int out_size, void* d_ws, size_t ws_size,
                              hipStream_t stream) {
  const float* x   = (const float*)d_in[0];
  const int*   ei  = (const int*)d_in[1];
  const float* W0  = (const float*)d_in[2];
  const float* a0s = (const float*)d_in[3];
  const float* a0d = (const float*)d_in[4];
  const float* b0  = (const float*)d_in[5];
  const float* W1  = (const float*)d_in[6];
  const float* a1s = (const float*)d_in[7];
  const float* a1d = (const float*)d_in[8];
  const float* b1  = (const float*)d_in[9];
  const float* W2  = (const float*)d_in[10];
  const float* a2s = (const float*)d_in[11];
  const float* a2d = (const float*)d_in[12];
  const float* b2  = (const float*)d_in[13];

  const int IN = 256;
  const int N = in_sizes[0] / IN;       // 50000
  const int E = in_sizes[1] / 2;        // 600000
  const int Etot = E + N;

  char* ws = (char*)d_ws;
  size_t off = 0;
  auto alloc = [&](size_t bytes) {
    void* p = ws + off;
    off += (bytes + 255) & ~(size_t)255;
    return p;
  };
  float*  A       = (float*)alloc((size_t)N * 256 * 4);
  float*  Bbuf    = (float*)alloc((size_t)N * 256 * 4);
  __half* A16     = (__half*)alloc((size_t)N * 256 * 2);
  float*  as_buf  = (float*)alloc((size_t)N * 4 * 4);
  float*  ad_buf  = (float*)alloc((size_t)N * 4 * 4);
  int*    row_ptr = (int*)alloc((size_t)(N + 1) * 4);
  int*    cursor  = (int*)alloc((size_t)N * 4);
  int*    cnt     = (int*)alloc((size_t)N * 4);
  int*    col_src = (int*)alloc((size_t)Etot * 4);

  // ---- CSR build ----
  zero_int_kernel<<<(N + 255) / 256, 256, 0, stream>>>(cnt, N);
  count_kernel<<<(Etot + 255) / 256, 256, 0, stream>>>(ei, E, N, cnt);
  scan_kernel<<<1, 1024, 0, stream>>>(cnt, row_ptr, cursor, N);
  fill_kernel<<<(Etot + 255) / 256, 256, 0, stream>>>(ei, E, N, cursor, col_src);

  dim3 g0(256 / 128, (N + 127) / 128);  // 2 x 391
  dim3 g2(64 / 64, (N + 127) / 128);    // 1 x 391
  int node_blocks = (N + 3) / 4;        // 4 waves/block, 1 wave/node

  // ---- layer 0 ----
  sgemm_kernel<128, 128><<<g0, 256, 0, stream>>>(x, W0, A, A16, N, 256, 256);
  alpha_kernel<4, 64><<<node_blocks, 256, 0, stream>>>(A, a0s, a0d, as_buf, ad_buf, N);
  aggregate4_kernel<true><<<node_blocks, 256, 0, stream>>>(
      A16, as_buf, ad_buf, row_ptr, col_src, b0, Bbuf, N);

  // ---- layer 1 ----
  sgemm_kernel<128, 128><<<g0, 256, 0, stream>>>(Bbuf, W1, A, A16, N, 256, 256);
  alpha_kernel<4, 64><<<node_blocks, 256, 0, stream>>>(A, a1s, a1d, as_buf, ad_buf, N);
  aggregate4_kernel<true><<<node_blocks, 256, 0, stream>>>(
      A16, as_buf, ad_buf, row_ptr, col_src, b1, Bbuf, N);

  // ---- layer 2 (H=1, ld=64) ----
  sgemm_kernel<128, 64><<<g2, 256, 0, stream>>>(Bbuf, W2, A, A16, N, 64, 256);
  alpha_kernel<1, 64><<<node_blocks, 256, 0, stream>>>(A, a2s, a2d, as_buf, ad_buf, N);
  aggregate1_kernel<false><<<node_blocks, 256, 0, stream>>>(
      A16, as_buf, ad_buf, row_ptr, col_src, b2, (float*)d_out, N);
}

// Round 8
// 565.403 us; speedup vs baseline: 1.3696x; 1.1955x over previous
//
#include <hip/hip_runtime.h>
#include <hip/hip_fp16.h>

#define NEG_SLOPE 0.2f

typedef _Float16 f16x8 __attribute__((ext_vector_type(8)));
typedef _Float16 f16x4 __attribute__((ext_vector_type(4)));
typedef float f32x4 __attribute__((ext_vector_type(4)));

// ---------------------------------------------------------------- CSR build
__global__ void zero_int_kernel(int* __restrict__ p, int n) {
  int i = blockIdx.x * blockDim.x + threadIdx.x;
  if (i < n) p[i] = 0;
}

__global__ void count_kernel(const int* __restrict__ ei, int E, int N,
                             int* __restrict__ cnt) {
  int e = blockIdx.x * blockDim.x + threadIdx.x;
  int tot = E + N;
  if (e >= tot) return;
  int dst = (e < E) ? ei[E + e] : (e - E);
  atomicAdd(&cnt[dst], 1);
}

// 1024 threads, one block. Per-thread serial chunk + shuffle block-scan.
__global__ __launch_bounds__(1024) void scan_kernel(const int* __restrict__ cnt,
                                                    int* __restrict__ row_ptr,
                                                    int* __restrict__ cursor,
                                                    int N) {
  int t = threadIdx.x;
  int CH = (N + 1023) >> 10;
  int b = t * CH; if (b > N) b = N;
  int e = b + CH; if (e > N) e = N;
  int sum = 0;
  for (int i = b; i < e; ++i) sum += cnt[i];
  int lane = t & 63, wid = t >> 6;
  int v = sum;
#pragma unroll
  for (int off = 1; off < 64; off <<= 1) {
    int u = __shfl_up(v, off, 64);
    if (lane >= off) v += u;
  }
  __shared__ int wsum[16];
  __shared__ int wpre[16];
  if (lane == 63) wsum[wid] = v;
  __syncthreads();
  if (t < 16) {
    int wv = wsum[t];
#pragma unroll
    for (int off = 1; off < 16; off <<= 1) {
      int u = __shfl_up(wv, off, 16);
      if (t >= off) wv += u;
    }
    wpre[t] = wv - wsum[t];
  }
  __syncthreads();
  int run = wpre[wid] + (v - sum);
  for (int i = b; i < e; ++i) {
    int c = cnt[i];
    row_ptr[i] = run;
    cursor[i] = run;
    run += c;
  }
  if (t == 1023) row_ptr[N] = run;
}

__global__ void fill_kernel(const int* __restrict__ ei, int E, int N,
                            int* __restrict__ cursor, int* __restrict__ col_src) {
  int e = blockIdx.x * blockDim.x + threadIdx.x;
  int tot = E + N;
  if (e >= tot) return;
  int src, dst;
  if (e < E) { src = ei[e]; dst = ei[E + e]; } else { src = e - E; dst = e - E; }
  int pos = atomicAdd(&cursor[dst], 1);
  col_src[pos] = src;
}

// ------------------------------------------------- split-fp16 MFMA GEMM
// Y[M,N] = X[M,K] @ W[K,N] in effectively-fp32 precision:
// X = Xh + Xl, W = Wh + Wl (fp16 hi/lo); Y ~= Xh*Wh + Xh*Wl + Xl*Wh
// (dropped Xl*Wl ~ 2^-22 relative). fp32 MFMA accumulate.
// Layouts (verified, guide §3/m89/m91/m120):
//   A-frag: lane holds A[m=lane&15][k=quad*8+j]
//   B-frag: lane holds B[k=quad*8+j][n=lane&15]  (LDS stores B n-major)
//   C/D   : col=lane&15, row=quad*4+reg
template <int BN>
__global__ __launch_bounds__(256) void mfma_gemm(const float* __restrict__ X,
                                                 const float* __restrict__ W,
                                                 float* __restrict__ Y,
                                                 __half* __restrict__ Y16,
                                                 int M, int N, int K) {
  constexpr int BM = 128, BK = 32;
  constexpr int LDK = BK + 8;               // +16B pad per row
  constexpr int MI = (BN == 128) ? 4 : 2;   // 16-row tiles per wave
  constexpr int NI = 4;                     // 16-col tiles per wave
  constexpr int CK = BN / 8;                // k's per thread for B staging
  __shared__ _Float16 Ah[BM][LDK];
  __shared__ _Float16 Al[BM][LDK];
  __shared__ _Float16 Bh[BN][LDK];
  __shared__ _Float16 Bl[BN][LDK];
  int tid = threadIdx.x;
  int wave = tid >> 6, lane = tid & 63;
  int quad = lane >> 4, l16 = lane & 15;
  int br = blockIdx.y * BM, bc = blockIdx.x * BN;
  int wm = (BN == 128) ? (wave >> 1) * 64 : wave * 32;
  int wn = (BN == 128) ? (wave & 1) * 64 : 0;
  int bn = tid % BN;                // B staging: my column
  int bkh = (tid / BN) * CK;        // B staging: my k-range start

  f32x4 acc[MI][NI] = {};

  for (int k0 = 0; k0 < K; k0 += BK) {
    // ---- stage A: BM x BK fp32 -> hi/lo fp16, row-major k-contiguous ----
#pragma unroll
    for (int i = 0; i < 4; ++i) {
      int f = tid + i * 256;        // 1024 float4-slots: row = f>>3, kq=(f&7)*4
      int row = f >> 3;
      int kq = (f & 7) * 4;
      int gm = br + row;
      float4 v = make_float4(0.f, 0.f, 0.f, 0.f);
      if (gm < M) v = *(const float4*)&X[(size_t)gm * K + k0 + kq];
      f16x4 hi, lo;
      hi[0] = (_Float16)v.x; lo[0] = (_Float16)(v.x - (float)hi[0]);
      hi[1] = (_Float16)v.y; lo[1] = (_Float16)(v.y - (float)hi[1]);
      hi[2] = (_Float16)v.z; lo[2] = (_Float16)(v.z - (float)hi[2]);
      hi[3] = (_Float16)v.w; lo[3] = (_Float16)(v.w - (float)hi[3]);
      *(f16x4*)&Ah[row][kq] = hi;
      *(f16x4*)&Al[row][kq] = lo;
    }
    // ---- stage B: BK x BN fp32 -> hi/lo fp16, stored n-major (transposed) ----
    {
      float tmp[CK];
#pragma unroll
      for (int i = 0; i < CK; ++i)
        tmp[i] = W[(size_t)(k0 + bkh + i) * N + bc + bn];
#pragma unroll
      for (int c = 0; c < CK / 8; ++c) {
        f16x8 hi8, lo8;
#pragma unroll
        for (int j = 0; j < 8; ++j) {
          float v = tmp[c * 8 + j];
          _Float16 h = (_Float16)v;
          hi8[j] = h;
          lo8[j] = (_Float16)(v - (float)h);
        }
        *(f16x8*)&Bh[bn][bkh + c * 8] = hi8;
        *(f16x8*)&Bl[bn][bkh + c * 8] = lo8;
      }
    }
    __syncthreads();
    // ---- fragments ----
    f16x8 fah[MI], fal[MI], fbh[NI], fbl[NI];
#pragma unroll
    for (int mi = 0; mi < MI; ++mi) {
      int row = wm + mi * 16 + l16;
      fah[mi] = *(const f16x8*)&Ah[row][quad * 8];
      fal[mi] = *(const f16x8*)&Al[row][quad * 8];
    }
#pragma unroll
    for (int ni = 0; ni < NI; ++ni) {
      int col = wn + ni * 16 + l16;
      fbh[ni] = *(const f16x8*)&Bh[col][quad * 8];
      fbl[ni] = *(const f16x8*)&Bl[col][quad * 8];
    }
    // ---- 3-term split MFMA ----
#pragma unroll
    for (int mi = 0; mi < MI; ++mi)
#pragma unroll
      for (int ni = 0; ni < NI; ++ni) {
        acc[mi][ni] = __builtin_amdgcn_mfma_f32_16x16x32_f16(
            fah[mi], fbh[ni], acc[mi][ni], 0, 0, 0);
        acc[mi][ni] = __builtin_amdgcn_mfma_f32_16x16x32_f16(
            fah[mi], fbl[ni], acc[mi][ni], 0, 0, 0);
        acc[mi][ni] = __builtin_amdgcn_mfma_f32_16x16x32_f16(
            fal[mi], fbh[ni], acc[mi][ni], 0, 0, 0);
      }
    __syncthreads();
  }

  // ---- epilogue: C/D layout col=l16, row=quad*4+reg ----
#pragma unroll
  for (int mi = 0; mi < MI; ++mi) {
#pragma unroll
    for (int r = 0; r < 4; ++r) {
      int grow = br + wm + mi * 16 + quad * 4 + r;
      if (grow >= M) continue;
#pragma unroll
      for (int ni = 0; ni < NI; ++ni) {
        int gcol = bc + wn + ni * 16 + l16;
        float v = acc[mi][ni][r];
        Y[(size_t)grow * N + gcol] = v;
        Y16[(size_t)grow * N + gcol] = __float2half(v);
      }
    }
  }
}

// ------------------------------------------------- per-node alpha_s/alpha_d
template <int H, int C>
__global__ void alpha_kernel(const float* __restrict__ h,
                             const float* __restrict__ a_s,
                             const float* __restrict__ a_d,
                             float* __restrict__ out_s,
                             float* __restrict__ out_d, int N) {
  constexpr int HC = H * C;
  constexpr int PER = HC / 64;
  constexpr int SEG = C / PER;
  int lane = threadIdx.x & 63;
  int node = (blockIdx.x * blockDim.x + threadIdx.x) >> 6;
  if (node >= N) return;
  int cbase = lane * PER;
  const float* row = h + (size_t)node * HC + cbase;
  float ss, dd;
  if constexpr (PER == 4) {
    float4 v = *(const float4*)row;
    float4 s4 = *(const float4*)(a_s + cbase);
    float4 d4 = *(const float4*)(a_d + cbase);
    ss = v.x * s4.x + v.y * s4.y + v.z * s4.z + v.w * s4.w;
    dd = v.x * d4.x + v.y * d4.y + v.z * d4.z + v.w * d4.w;
  } else {
    float v = row[0];
    ss = v * a_s[cbase];
    dd = v * a_d[cbase];
  }
#pragma unroll
  for (int off = SEG >> 1; off >= 1; off >>= 1) {
    ss += __shfl_xor(ss, off, 64);
    dd += __shfl_xor(dd, off, 64);
  }
  if ((lane % SEG) == 0) {
    int head = lane / SEG;
    out_s[(size_t)node * H + head] = ss;
    out_d[(size_t)node * H + head] = dd;
  }
}

// helper: gather 4 consecutive halfs (8B) and fma into facc with weight w
__device__ __forceinline__ void fma_h4(const __half* p, float w, float* facc) {
  union { float2 f2; __half2 h2[2]; } c;
  c.f2 = *(const float2*)p;
  float2 lo = __half22float2(c.h2[0]);
  float2 hi = __half22float2(c.h2[1]);
  facc[0] += lo.x * w; facc[1] += lo.y * w;
  facc[2] += hi.x * w; facc[3] += hi.y * w;
}

// ------------------------------- segment softmax + mean-aggregate + bias(+relu)
// One wave per dst node; gathers fp16 h rows (half traffic of fp32).
// NOTE: __shfl(expr, i) evaluates expr on the SOURCE lane — head-dependent
// select must happen AFTER the shuffle.
template <bool RELU>
__global__ void aggregate4_kernel(const __half* __restrict__ h16,
                                  const float* __restrict__ as_,
                                  const float* __restrict__ ad_,
                                  const int* __restrict__ row_ptr,
                                  const int* __restrict__ col_src,
                                  const float* __restrict__ bias,
                                  float* __restrict__ out, int N) {
  int lane = threadIdx.x & 63;
  int node = (blockIdx.x * blockDim.x + threadIdx.x) >> 6;
  if (node >= N) return;
  int beg = row_ptr[node], end = row_ptr[node + 1];
  int deg = end - beg;
  float inv_deg = 1.f / (float)deg;
  int myhead = lane >> 4;
  float facc[4] = {};
  float4 adv4 = *(const float4*)(ad_ + (size_t)node * 4);
  const __half* hl = h16 + lane * 4;   // + s*256 per edge

  if (deg <= 16) {
    int head_w = lane >> 4, e_w = lane & 15;
    float q = 0.f; int s_w = 0;
    if (e_w < deg) {
      s_w = col_src[beg + e_w];
      float4 a4 = *(const float4*)(as_ + (size_t)s_w * 4);
      float av = head_w == 0 ? a4.x : head_w == 1 ? a4.y : head_w == 2 ? a4.z : a4.w;
      float dv = head_w == 0 ? adv4.x : head_w == 1 ? adv4.y : head_w == 2 ? adv4.z : adv4.w;
      float e = av + dv;
      e = (e > 0.f) ? e : NEG_SLOPE * e;
      q = __expf(e);
    }
    float dn = q;
    dn += __shfl_xor(dn, 1, 64);
    dn += __shfl_xor(dn, 2, 64);
    dn += __shfl_xor(dn, 4, 64);
    dn += __shfl_xor(dn, 8, 64);
    float qs = q * (1.f / dn) * inv_deg;
    int base = myhead << 4;
    int i = 0;
    for (; i + 4 <= deg; i += 4) {
      int s0 = __shfl(s_w, base + i + 0, 64); float w0 = __shfl(qs, base + i + 0, 64);
      int s1 = __shfl(s_w, base + i + 1, 64); float w1 = __shfl(qs, base + i + 1, 64);
      int s2 = __shfl(s_w, base + i + 2, 64); float w2 = __shfl(qs, base + i + 2, 64);
      int s3 = __shfl(s_w, base + i + 3, 64); float w3 = __shfl(qs, base + i + 3, 64);
      fma_h4(hl + (size_t)s0 * 256, w0, facc);
      fma_h4(hl + (size_t)s1 * 256, w1, facc);
      fma_h4(hl + (size_t)s2 * 256, w2, facc);
      fma_h4(hl + (size_t)s3 * 256, w3, facc);
    }
    for (; i < deg; ++i) {
      int srcn = __shfl(s_w, base + i, 64);
      float w = __shfl(qs, base + i, 64);
      fma_h4(hl + (size_t)srcn * 256, w, facc);
    }
  } else if (deg <= 64) {
    float p0 = 0.f, p1 = 0.f, p2 = 0.f, p3 = 0.f; int s_w = 0;
    if (lane < deg) {
      s_w = col_src[beg + lane];
      float4 a4 = *(const float4*)(as_ + (size_t)s_w * 4);
      float e0 = a4.x + adv4.x; e0 = e0 > 0.f ? e0 : NEG_SLOPE * e0; p0 = __expf(e0);
      float e1 = a4.y + adv4.y; e1 = e1 > 0.f ? e1 : NEG_SLOPE * e1; p1 = __expf(e1);
      float e2 = a4.z + adv4.z; e2 = e2 > 0.f ? e2 : NEG_SLOPE * e2; p2 = __expf(e2);
      float e3 = a4.w + adv4.w; e3 = e3 > 0.f ? e3 : NEG_SLOPE * e3; p3 = __expf(e3);
    }
    float d0 = p0, d1 = p1, d2 = p2, d3 = p3;
#pragma unroll
    for (int off = 32; off >= 1; off >>= 1) {
      d0 += __shfl_xor(d0, off, 64);
      d1 += __shfl_xor(d1, off, 64);
      d2 += __shfl_xor(d2, off, 64);
      d3 += __shfl_xor(d3, off, 64);
    }
    p0 *= (1.f / d0) * inv_deg;
    p1 *= (1.f / d1) * inv_deg;
    p2 *= (1.f / d2) * inv_deg;
    p3 *= (1.f / d3) * inv_deg;
    int i = 0;
    for (; i + 2 <= deg; i += 2) {
      int s0 = __shfl(s_w, i + 0, 64);
      int s1 = __shfl(s_w, i + 1, 64);
      float a00 = __shfl(p0, i + 0, 64), a01 = __shfl(p1, i + 0, 64);
      float a02 = __shfl(p2, i + 0, 64), a03 = __shfl(p3, i + 0, 64);
      float a10 = __shfl(p0, i + 1, 64), a11 = __shfl(p1, i + 1, 64);
      float a12 = __shfl(p2, i + 1, 64), a13 = __shfl(p3, i + 1, 64);
      float w0 = myhead == 0 ? a00 : myhead == 1 ? a01 : myhead == 2 ? a02 : a03;
      float w1 = myhead == 0 ? a10 : myhead == 1 ? a11 : myhead == 2 ? a12 : a13;
      fma_h4(hl + (size_t)s0 * 256, w0, facc);
      fma_h4(hl + (size_t)s1 * 256, w1, facc);
    }
    for (; i < deg; ++i) {
      int srcn = __shfl(s_w, i, 64);
      float b0 = __shfl(p0, i, 64), b1 = __shfl(p1, i, 64);
      float b2 = __shfl(p2, i, 64), b3 = __shfl(p3, i, 64);
      float w = myhead == 0 ? b0 : myhead == 1 ? b1 : myhead == 2 ? b2 : b3;
      fma_h4(hl + (size_t)srcn * 256, w, facc);
    }
  } else {
    float dn0 = 0.f, dn1 = 0.f, dn2 = 0.f, dn3 = 0.f;
    for (int i = beg + lane; i < end; i += 64) {
      int s = col_src[i];
      float4 a4 = *(const float4*)(as_ + (size_t)s * 4);
      float e0 = a4.x + adv4.x; e0 = e0 > 0.f ? e0 : NEG_SLOPE * e0; dn0 += __expf(e0);
      float e1 = a4.y + adv4.y; e1 = e1 > 0.f ? e1 : NEG_SLOPE * e1; dn1 += __expf(e1);
      float e2 = a4.z + adv4.z; e2 = e2 > 0.f ? e2 : NEG_SLOPE * e2; dn2 += __expf(e2);
      float e3 = a4.w + adv4.w; e3 = e3 > 0.f ? e3 : NEG_SLOPE * e3; dn3 += __expf(e3);
    }
#pragma unroll
    for (int off = 32; off >= 1; off >>= 1) {
      dn0 += __shfl_xor(dn0, off, 64);
      dn1 += __shfl_xor(dn1, off, 64);
      dn2 += __shfl_xor(dn2, off, 64);
      dn3 += __shfl_xor(dn3, off, 64);
    }
    float adm = myhead == 0 ? adv4.x : myhead == 1 ? adv4.y : myhead == 2 ? adv4.z : adv4.w;
    float invdn = 1.f / (myhead == 0 ? dn0 : myhead == 1 ? dn1 : myhead == 2 ? dn2 : dn3);
    invdn *= inv_deg;
    for (int i = beg; i < end; ++i) {
      int s = col_src[i];
      float e = as_[(size_t)s * 4 + myhead] + adm;
      e = (e > 0.f) ? e : NEG_SLOPE * e;
      float w = __expf(e) * invdn;
      fma_h4(hl + (size_t)s * 256, w, facc);
    }
  }

  float* orow = out + (size_t)node * 256 + lane * 4;
#pragma unroll
  for (int p = 0; p < 4; ++p) {
    float v = facc[p] + bias[lane * 4 + p];
    if (RELU) v = fmaxf(v, 0.f);
    orow[p] = v;
  }
}

// --------------------------- aggregation, H=1 (layer 2): one wave per node
template <bool RELU>
__global__ void aggregate1_kernel(const __half* __restrict__ h16,
                                  const float* __restrict__ as_,
                                  const float* __restrict__ ad_,
                                  const int* __restrict__ row_ptr,
                                  const int* __restrict__ col_src,
                                  const float* __restrict__ bias,
                                  float* __restrict__ out, int N) {
  int lane = threadIdx.x & 63;
  int node = (blockIdx.x * blockDim.x + threadIdx.x) >> 6;
  if (node >= N) return;
  int beg = row_ptr[node], end = row_ptr[node + 1];
  int deg = end - beg;
  float inv_deg = 1.f / (float)deg;
  float adv = ad_[node];
  const __half* hb = h16 + lane;
  float facc = 0.f;

  if (deg <= 64) {
    float q = 0.f; int s_w = 0;
    if (lane < deg) {
      s_w = col_src[beg + lane];
      float e = as_[s_w] + adv;
      e = (e > 0.f) ? e : NEG_SLOPE * e;
      q = __expf(e);
    }
    float dn = q;
#pragma unroll
    for (int off = 32; off >= 1; off >>= 1) dn += __shfl_xor(dn, off, 64);
    float qs = q * (1.f / dn) * inv_deg;
    int deg8 = (deg + 7) & ~7;
    for (int i = 0; i < deg8; i += 8) {
      int s0 = __shfl(s_w, i + 0, 64); float w0 = __shfl(qs, i + 0, 64);
      int s1 = __shfl(s_w, i + 1, 64); float w1 = __shfl(qs, i + 1, 64);
      int s2 = __shfl(s_w, i + 2, 64); float w2 = __shfl(qs, i + 2, 64);
      int s3 = __shfl(s_w, i + 3, 64); float w3 = __shfl(qs, i + 3, 64);
      int s4 = __shfl(s_w, i + 4, 64); float w4 = __shfl(qs, i + 4, 64);
      int s5 = __shfl(s_w, i + 5, 64); float w5 = __shfl(qs, i + 5, 64);
      int s6 = __shfl(s_w, i + 6, 64); float w6 = __shfl(qs, i + 6, 64);
      int s7 = __shfl(s_w, i + 7, 64); float w7 = __shfl(qs, i + 7, 64);
      float v0 = __half2float(hb[(size_t)s0 * 64]);
      float v1 = __half2float(hb[(size_t)s1 * 64]);
      float v2 = __half2float(hb[(size_t)s2 * 64]);
      float v3 = __half2float(hb[(size_t)s3 * 64]);
      float v4 = __half2float(hb[(size_t)s4 * 64]);
      float v5 = __half2float(hb[(size_t)s5 * 64]);
      float v6 = __half2float(hb[(size_t)s6 * 64]);
      float v7 = __half2float(hb[(size_t)s7 * 64]);
      facc += v0 * w0 + v1 * w1 + v2 * w2 + v3 * w3;
      facc += v4 * w4 + v5 * w5 + v6 * w6 + v7 * w7;
    }
  } else {
    float dn = 0.f;
    for (int i = beg + lane; i < end; i += 64) {
      int s = col_src[i];
      float e = as_[s] + adv;
      e = (e > 0.f) ? e : NEG_SLOPE * e;
      dn += __expf(e);
    }
#pragma unroll
    for (int off = 32; off >= 1; off >>= 1) dn += __shfl_xor(dn, off, 64);
    float scale = (1.f / dn) * inv_deg;
    for (int base = beg; base < end; base += 64) {
      int i2 = base + lane;
      float q2 = 0.f; int s2r = 0;
      if (i2 < end) {
        s2r = col_src[i2];
        float e = as_[s2r] + adv;
        e = (e > 0.f) ? e : NEG_SLOPE * e;
        q2 = __expf(e) * scale;
      }
      int cnt = end - base; if (cnt > 64) cnt = 64;
      for (int j = 0; j < cnt; ++j) {
        int s = __shfl(s2r, j, 64);
        float w = __shfl(q2, j, 64);
        facc += __half2float(hb[(size_t)s * 64]) * w;
      }
    }
  }

  float vout = facc + bias[lane];
  if (RELU) vout = fmaxf(vout, 0.f);
  out[(size_t)node * 64 + lane] = vout;
}

// ---------------------------------------------------------------- launcher
extern "C" void kernel_launch(void* const* d_in, const int* in_sizes, int n_in,
                              void* d_out, int out_size, void* d_ws, size_t ws_size,
                              hipStream_t stream) {
  const float* x   = (const float*)d_in[0];
  const int*   ei  = (const int*)d_in[1];
  const float* W0  = (const float*)d_in[2];
  const float* a0s = (const float*)d_in[3];
  const float* a0d = (const float*)d_in[4];
  const float* b0  = (const float*)d_in[5];
  const float* W1  = (const float*)d_in[6];
  const float* a1s = (const float*)d_in[7];
  const float* a1d = (const float*)d_in[8];
  const float* b1  = (const float*)d_in[9];
  const float* W2  = (const float*)d_in[10];
  const float* a2s = (const float*)d_in[11];
  const float* a2d = (const float*)d_in[12];
  const float* b2  = (const float*)d_in[13];

  const int IN = 256;
  const int N = in_sizes[0] / IN;       // 50000
  const int E = in_sizes[1] / 2;        // 600000
  const int Etot = E + N;

  char* ws = (char*)d_ws;
  size_t off = 0;
  auto alloc = [&](size_t bytes) {
    void* p = ws + off;
    off += (bytes + 255) & ~(size_t)255;
    return p;
  };
  float*  A       = (float*)alloc((size_t)N * 256 * 4);
  float*  Bbuf    = (float*)alloc((size_t)N * 256 * 4);
  __half* A16     = (__half*)alloc((size_t)N * 256 * 2);
  float*  as_buf  = (float*)alloc((size_t)N * 4 * 4);
  float*  ad_buf  = (float*)alloc((size_t)N * 4 * 4);
  int*    row_ptr = (int*)alloc((size_t)(N + 1) * 4);
  int*    cursor  = (int*)alloc((size_t)N * 4);
  int*    cnt     = (int*)alloc((size_t)N * 4);
  int*    col_src = (int*)alloc((size_t)Etot * 4);

  // ---- CSR build ----
  zero_int_kernel<<<(N + 255) / 256, 256, 0, stream>>>(cnt, N);
  count_kernel<<<(Etot + 255) / 256, 256, 0, stream>>>(ei, E, N, cnt);
  scan_kernel<<<1, 1024, 0, stream>>>(cnt, row_ptr, cursor, N);
  fill_kernel<<<(Etot + 255) / 256, 256, 0, stream>>>(ei, E, N, cursor, col_src);

  dim3 g0(256 / 128, (N + 127) / 128);  // 2 x 391
  dim3 g2(64 / 64, (N + 127) / 128);    // 1 x 391
  int node_blocks = (N + 3) / 4;        // 4 waves/block, 1 wave/node

  // ---- layer 0 ----
  mfma_gemm<128><<<g0, 256, 0, stream>>>(x, W0, A, A16, N, 256, 256);
  alpha_kernel<4, 64><<<node_blocks, 256, 0, stream>>>(A, a0s, a0d, as_buf, ad_buf, N);
  aggregate4_kernel<true><<<node_blocks, 256, 0, stream>>>(
      A16, as_buf, ad_buf, row_ptr, col_src, b0, Bbuf, N);

  // ---- layer 1 ----
  mfma_gemm<128><<<g0, 256, 0, stream>>>(Bbuf, W1, A, A16, N, 256, 256);
  alpha_kernel<4, 64><<<node_blocks, 256, 0, stream>>>(A, a1s, a1d, as_buf, ad_buf, N);
  aggregate4_kernel<true><<<node_blocks, 256, 0, stream>>>(
      A16, as_buf, ad_buf, row_ptr, col_src, b1, Bbuf, N);

  // ---- layer 2 (H=1, ld=64) ----
  mfma_gemm<64><<<g2, 256, 0, stream>>>(Bbuf, W2, A, A16, N, 64, 256);
  alpha_kernel<1, 64><<<node_blocks, 256, 0, stream>>>(A, a2s, a2d, as_buf, ad_buf, N);
  aggregate1_kernel<false><<<node_blocks, 256, 0, stream>>>(
      A16, as_buf, ad_buf, row_ptr, col_src, b2, (float*)d_out, N);
}

// Round 9
// 461.024 us; speedup vs baseline: 1.6796x; 1.2264x over previous
//
#include <hip/hip_runtime.h>
#include <hip/hip_fp16.h>

#define NEG_SLOPE 0.2f

typedef _Float16 f16x8 __attribute__((ext_vector_type(8)));
typedef _Float16 f16x4 __attribute__((ext_vector_type(4)));
typedef float f32x4 __attribute__((ext_vector_type(4)));

// ---------------------------------------------------------------- CSR build
__global__ void zero_int_kernel(int* __restrict__ p, int n) {
  int i = blockIdx.x * blockDim.x + threadIdx.x;
  if (i < n) p[i] = 0;
}

__global__ void count_kernel(const int* __restrict__ ei, int E, int N,
                             int* __restrict__ cnt) {
  int e = blockIdx.x * blockDim.x + threadIdx.x;
  int tot = E + N;
  if (e >= tot) return;
  int dst = (e < E) ? ei[E + e] : (e - E);
  atomicAdd(&cnt[dst], 1);
}

// --- parallel scan, 3 tiny kernels (round-8 single-block scan was 110 us) ---
// scanA: each 256-thread block scans a 1024-element tile (4/thread, int4).
__global__ __launch_bounds__(256) void scanA_kernel(const int* __restrict__ cnt,
                                                    int* __restrict__ locex,
                                                    int* __restrict__ blk_sum,
                                                    int N) {
  int t = threadIdx.x;
  int base = blockIdx.x * 1024 + t * 4;
  int a0 = 0, a1 = 0, a2 = 0, a3 = 0;
  if (base + 3 < N) {
    int4 v = *(const int4*)&cnt[base];
    a0 = v.x; a1 = v.y; a2 = v.z; a3 = v.w;
  } else if (base < N) {
    a0 = cnt[base];
    if (base + 1 < N) a1 = cnt[base + 1];
    if (base + 2 < N) a2 = cnt[base + 2];
  }
  int s1 = a0 + a1, s2 = s1 + a2, s3 = s2 + a3;
  int tot = s3;
  int lane = t & 63, wid = t >> 6;
  int ws = tot;
#pragma unroll
  for (int off = 1; off < 64; off <<= 1) {
    int u = __shfl_up(ws, off, 64);
    if (lane >= off) ws += u;
  }
  __shared__ int wsum[4];
  __shared__ int woff[4];
  if (lane == 63) wsum[wid] = ws;
  __syncthreads();
  if (t == 0) {
    int r = 0;
#pragma unroll
    for (int i = 0; i < 4; ++i) { woff[i] = r; r += wsum[i]; }
    blk_sum[blockIdx.x] = r;
  }
  __syncthreads();
  int ex = woff[wid] + (ws - tot);   // exclusive prefix of this thread in block
  int o0 = ex, o1 = ex + a0, o2 = ex + s1, o3 = ex + s2;
  if (base + 3 < N) {
    *(int4*)&locex[base] = make_int4(o0, o1, o2, o3);
  } else if (base < N) {
    locex[base] = o0;
    if (base + 1 < N) locex[base + 1] = o1;
    if (base + 2 < N) locex[base + 2] = o2;
  }
}

// scanB: one wave exclusive-scans nb block totals (chunked; any nb).
__global__ void scanB_kernel(const int* __restrict__ blk_sum,
                             int* __restrict__ blk_off,
                             int* __restrict__ row_ptr, int nb, int N) {
  int t = threadIdx.x;   // 64 threads
  int run = 0;
  for (int c = 0; c < nb; c += 64) {
    int idx = c + t;
    int v = (idx < nb) ? blk_sum[idx] : 0;
    int inc = v;
#pragma unroll
    for (int off = 1; off < 64; off <<= 1) {
      int u = __shfl_up(inc, off, 64);
      if (t >= off) inc += u;
    }
    if (idx < nb) blk_off[idx] = run + inc - v;
    run += __shfl(inc, 63, 64);
  }
  if (t == 0) row_ptr[N] = run;
}

// scanC: add tile offset, write row_ptr + cursor.
__global__ void scanC_kernel(const int* __restrict__ locex,
                             const int* __restrict__ blk_off,
                             int* __restrict__ row_ptr,
                             int* __restrict__ cursor, int N) {
  int i = blockIdx.x * blockDim.x + threadIdx.x;
  if (i >= N) return;
  int v = blk_off[i >> 10] + locex[i];
  row_ptr[i] = v;
  cursor[i] = v;
}

__global__ void fill_kernel(const int* __restrict__ ei, int E, int N,
                            int* __restrict__ cursor, int* __restrict__ col_src) {
  int e = blockIdx.x * blockDim.x + threadIdx.x;
  int tot = E + N;
  if (e >= tot) return;
  int src, dst;
  if (e < E) { src = ei[e]; dst = ei[E + e]; } else { src = e - E; dst = e - E; }
  int pos = atomicAdd(&cursor[dst], 1);
  col_src[pos] = src;
}

// ------------------------------------------------- split-fp16 MFMA GEMM
// Y[M,N] = X[M,K] @ W[K,N] in effectively-fp32 precision:
// X = Xh + Xl, W = Wh + Wl (fp16 hi/lo); Y ~= Xh*Wh + Xh*Wl + Xl*Wh
// (dropped Xl*Wl ~ 2^-22 relative). fp32 MFMA accumulate.
template <int BN>
__global__ __launch_bounds__(256) void mfma_gemm(const float* __restrict__ X,
                                                 const float* __restrict__ W,
                                                 float* __restrict__ Y,
                                                 __half* __restrict__ Y16,
                                                 int M, int N, int K) {
  constexpr int BM = 128, BK = 32;
  constexpr int LDK = BK + 8;               // +16B pad per row
  constexpr int MI = (BN == 128) ? 4 : 2;   // 16-row tiles per wave
  constexpr int NI = 4;                     // 16-col tiles per wave
  constexpr int CK = BN / 8;                // k's per thread for B staging
  __shared__ _Float16 Ah[BM][LDK];
  __shared__ _Float16 Al[BM][LDK];
  __shared__ _Float16 Bh[BN][LDK];
  __shared__ _Float16 Bl[BN][LDK];
  int tid = threadIdx.x;
  int wave = tid >> 6, lane = tid & 63;
  int quad = lane >> 4, l16 = lane & 15;
  int br = blockIdx.y * BM, bc = blockIdx.x * BN;
  int wm = (BN == 128) ? (wave >> 1) * 64 : wave * 32;
  int wn = (BN == 128) ? (wave & 1) * 64 : 0;
  int bn = tid % BN;                // B staging: my column
  int bkh = (tid / BN) * CK;        // B staging: my k-range start

  f32x4 acc[MI][NI] = {};

  for (int k0 = 0; k0 < K; k0 += BK) {
#pragma unroll
    for (int i = 0; i < 4; ++i) {
      int f = tid + i * 256;
      int row = f >> 3;
      int kq = (f & 7) * 4;
      int gm = br + row;
      float4 v = make_float4(0.f, 0.f, 0.f, 0.f);
      if (gm < M) v = *(const float4*)&X[(size_t)gm * K + k0 + kq];
      f16x4 hi, lo;
      hi[0] = (_Float16)v.x; lo[0] = (_Float16)(v.x - (float)hi[0]);
      hi[1] = (_Float16)v.y; lo[1] = (_Float16)(v.y - (float)hi[1]);
      hi[2] = (_Float16)v.z; lo[2] = (_Float16)(v.z - (float)hi[2]);
      hi[3] = (_Float16)v.w; lo[3] = (_Float16)(v.w - (float)hi[3]);
      *(f16x4*)&Ah[row][kq] = hi;
      *(f16x4*)&Al[row][kq] = lo;
    }
    {
      float tmp[CK];
#pragma unroll
      for (int i = 0; i < CK; ++i)
        tmp[i] = W[(size_t)(k0 + bkh + i) * N + bc + bn];
#pragma unroll
      for (int c = 0; c < CK / 8; ++c) {
        f16x8 hi8, lo8;
#pragma unroll
        for (int j = 0; j < 8; ++j) {
          float v = tmp[c * 8 + j];
          _Float16 h = (_Float16)v;
          hi8[j] = h;
          lo8[j] = (_Float16)(v - (float)h);
        }
        *(f16x8*)&Bh[bn][bkh + c * 8] = hi8;
        *(f16x8*)&Bl[bn][bkh + c * 8] = lo8;
      }
    }
    __syncthreads();
    f16x8 fah[MI], fal[MI], fbh[NI], fbl[NI];
#pragma unroll
    for (int mi = 0; mi < MI; ++mi) {
      int row = wm + mi * 16 + l16;
      fah[mi] = *(const f16x8*)&Ah[row][quad * 8];
      fal[mi] = *(const f16x8*)&Al[row][quad * 8];
    }
#pragma unroll
    for (int ni = 0; ni < NI; ++ni) {
      int col = wn + ni * 16 + l16;
      fbh[ni] = *(const f16x8*)&Bh[col][quad * 8];
      fbl[ni] = *(const f16x8*)&Bl[col][quad * 8];
    }
#pragma unroll
    for (int mi = 0; mi < MI; ++mi)
#pragma unroll
      for (int ni = 0; ni < NI; ++ni) {
        acc[mi][ni] = __builtin_amdgcn_mfma_f32_16x16x32_f16(
            fah[mi], fbh[ni], acc[mi][ni], 0, 0, 0);
        acc[mi][ni] = __builtin_amdgcn_mfma_f32_16x16x32_f16(
            fah[mi], fbl[ni], acc[mi][ni], 0, 0, 0);
        acc[mi][ni] = __builtin_amdgcn_mfma_f32_16x16x32_f16(
            fal[mi], fbh[ni], acc[mi][ni], 0, 0, 0);
      }
    __syncthreads();
  }

#pragma unroll
  for (int mi = 0; mi < MI; ++mi) {
#pragma unroll
    for (int r = 0; r < 4; ++r) {
      int grow = br + wm + mi * 16 + quad * 4 + r;
      if (grow >= M) continue;
#pragma unroll
      for (int ni = 0; ni < NI; ++ni) {
        int gcol = bc + wn + ni * 16 + l16;
        float v = acc[mi][ni][r];
        Y[(size_t)grow * N + gcol] = v;
        Y16[(size_t)grow * N + gcol] = __float2half(v);
      }
    }
  }
}

// ------------------------------------------------- per-node alpha_s/alpha_d
template <int H, int C>
__global__ void alpha_kernel(const float* __restrict__ h,
                             const float* __restrict__ a_s,
                             const float* __restrict__ a_d,
                             float* __restrict__ out_s,
                             float* __restrict__ out_d, int N) {
  constexpr int HC = H * C;
  constexpr int PER = HC / 64;
  constexpr int SEG = C / PER;
  int lane = threadIdx.x & 63;
  int node = (blockIdx.x * blockDim.x + threadIdx.x) >> 6;
  if (node >= N) return;
  int cbase = lane * PER;
  const float* row = h + (size_t)node * HC + cbase;
  float ss, dd;
  if constexpr (PER == 4) {
    float4 v = *(const float4*)row;
    float4 s4 = *(const float4*)(a_s + cbase);
    float4 d4 = *(const float4*)(a_d + cbase);
    ss = v.x * s4.x + v.y * s4.y + v.z * s4.z + v.w * s4.w;
    dd = v.x * d4.x + v.y * d4.y + v.z * d4.z + v.w * d4.w;
  } else {
    float v = row[0];
    ss = v * a_s[cbase];
    dd = v * a_d[cbase];
  }
#pragma unroll
  for (int off = SEG >> 1; off >= 1; off >>= 1) {
    ss += __shfl_xor(ss, off, 64);
    dd += __shfl_xor(dd, off, 64);
  }
  if ((lane % SEG) == 0) {
    int head = lane / SEG;
    out_s[(size_t)node * H + head] = ss;
    out_d[(size_t)node * H + head] = dd;
  }
}

// helper: gather 4 consecutive halfs (8B) and fma into facc with weight w
__device__ __forceinline__ void fma_h4(const __half* p, float w, float* facc) {
  union { float2 f2; __half2 h2[2]; } c;
  c.f2 = *(const float2*)p;
  float2 lo = __half22float2(c.h2[0]);
  float2 hi = __half22float2(c.h2[1]);
  facc[0] += lo.x * w; facc[1] += lo.y * w;
  facc[2] += hi.x * w; facc[3] += hi.y * w;
}

// ------------------------------- segment softmax + mean-aggregate + bias(+relu)
template <bool RELU>
__global__ void aggregate4_kernel(const __half* __restrict__ h16,
                                  const float* __restrict__ as_,
                                  const float* __restrict__ ad_,
                                  const int* __restrict__ row_ptr,
                                  const int* __restrict__ col_src,
                                  const float* __restrict__ bias,
                                  float* __restrict__ out, int N) {
  int lane = threadIdx.x & 63;
  int node = (blockIdx.x * blockDim.x + threadIdx.x) >> 6;
  if (node >= N) return;
  int beg = row_ptr[node], end = row_ptr[node + 1];
  int deg = end - beg;
  float inv_deg = 1.f / (float)deg;
  int myhead = lane >> 4;
  float facc[4] = {};
  float4 adv4 = *(const float4*)(ad_ + (size_t)node * 4);
  const __half* hl = h16 + lane * 4;   // + s*256 per edge

  if (deg <= 16) {
    int head_w = lane >> 4, e_w = lane & 15;
    float q = 0.f; int s_w = 0;
    if (e_w < deg) {
      s_w = col_src[beg + e_w];
      float4 a4 = *(const float4*)(as_ + (size_t)s_w * 4);
      float av = head_w == 0 ? a4.x : head_w == 1 ? a4.y : head_w == 2 ? a4.z : a4.w;
      float dv = head_w == 0 ? adv4.x : head_w == 1 ? adv4.y : head_w == 2 ? adv4.z : adv4.w;
      float e = av + dv;
      e = (e > 0.f) ? e : NEG_SLOPE * e;
      q = __expf(e);
    }
    float dn = q;
    dn += __shfl_xor(dn, 1, 64);
    dn += __shfl_xor(dn, 2, 64);
    dn += __shfl_xor(dn, 4, 64);
    dn += __shfl_xor(dn, 8, 64);
    float qs = q * (1.f / dn) * inv_deg;
    int base = myhead << 4;
    int i = 0;
    for (; i + 4 <= deg; i += 4) {
      int s0 = __shfl(s_w, base + i + 0, 64); float w0 = __shfl(qs, base + i + 0, 64);
      int s1 = __shfl(s_w, base + i + 1, 64); float w1 = __shfl(qs, base + i + 1, 64);
      int s2 = __shfl(s_w, base + i + 2, 64); float w2 = __shfl(qs, base + i + 2, 64);
      int s3 = __shfl(s_w, base + i + 3, 64); float w3 = __shfl(qs, base + i + 3, 64);
      fma_h4(hl + (size_t)s0 * 256, w0, facc);
      fma_h4(hl + (size_t)s1 * 256, w1, facc);
      fma_h4(hl + (size_t)s2 * 256, w2, facc);
      fma_h4(hl + (size_t)s3 * 256, w3, facc);
    }
    for (; i < deg; ++i) {
      int srcn = __shfl(s_w, base + i, 64);
      float w = __shfl(qs, base + i, 64);
      fma_h4(hl + (size_t)srcn * 256, w, facc);
    }
  } else if (deg <= 64) {
    float p0 = 0.f, p1 = 0.f, p2 = 0.f, p3 = 0.f; int s_w = 0;
    if (lane < deg) {
      s_w = col_src[beg + lane];
      float4 a4 = *(const float4*)(as_ + (size_t)s_w * 4);
      float e0 = a4.x + adv4.x; e0 = e0 > 0.f ? e0 : NEG_SLOPE * e0; p0 = __expf(e0);
      float e1 = a4.y + adv4.y; e1 = e1 > 0.f ? e1 : NEG_SLOPE * e1; p1 = __expf(e1);
      float e2 = a4.z + adv4.z; e2 = e2 > 0.f ? e2 : NEG_SLOPE * e2; p2 = __expf(e2);
      float e3 = a4.w + adv4.w; e3 = e3 > 0.f ? e3 : NEG_SLOPE * e3; p3 = __expf(e3);
    }
    float d0 = p0, d1 = p1, d2 = p2, d3 = p3;
#pragma unroll
    for (int off = 32; off >= 1; off >>= 1) {
      d0 += __shfl_xor(d0, off, 64);
      d1 += __shfl_xor(d1, off, 64);
      d2 += __shfl_xor(d2, off, 64);
      d3 += __shfl_xor(d3, off, 64);
    }
    p0 *= (1.f / d0) * inv_deg;
    p1 *= (1.f / d1) * inv_deg;
    p2 *= (1.f / d2) * inv_deg;
    p3 *= (1.f / d3) * inv_deg;
    int i = 0;
    for (; i + 2 <= deg; i += 2) {
      int s0 = __shfl(s_w, i + 0, 64);
      int s1 = __shfl(s_w, i + 1, 64);
      float a00 = __shfl(p0, i + 0, 64), a01 = __shfl(p1, i + 0, 64);
      float a02 = __shfl(p2, i + 0, 64), a03 = __shfl(p3, i + 0, 64);
      float a10 = __shfl(p0, i + 1, 64), a11 = __shfl(p1, i + 1, 64);
      float a12 = __shfl(p2, i + 1, 64), a13 = __shfl(p3, i + 1, 64);
      float w0 = myhead == 0 ? a00 : myhead == 1 ? a01 : myhead == 2 ? a02 : a03;
      float w1 = myhead == 0 ? a10 : myhead == 1 ? a11 : myhead == 2 ? a12 : a13;
      fma_h4(hl + (size_t)s0 * 256, w0, facc);
      fma_h4(hl + (size_t)s1 * 256, w1, facc);
    }
    for (; i < deg; ++i) {
      int srcn = __shfl(s_w, i, 64);
      float b0 = __shfl(p0, i, 64), b1 = __shfl(p1, i, 64);
      float b2 = __shfl(p2, i, 64), b3 = __shfl(p3, i, 64);
      float w = myhead == 0 ? b0 : myhead == 1 ? b1 : myhead == 2 ? b2 : b3;
      fma_h4(hl + (size_t)srcn * 256, w, facc);
    }
  } else {
    float dn0 = 0.f, dn1 = 0.f, dn2 = 0.f, dn3 = 0.f;
    for (int i = beg + lane; i < end; i += 64) {
      int s = col_src[i];
      float4 a4 = *(const float4*)(as_ + (size_t)s * 4);
      float e0 = a4.x + adv4.x; e0 = e0 > 0.f ? e0 : NEG_SLOPE * e0; dn0 += __expf(e0);
      float e1 = a4.y + adv4.y; e1 = e1 > 0.f ? e1 : NEG_SLOPE * e1; dn1 += __expf(e1);
      float e2 = a4.z + adv4.z; e2 = e2 > 0.f ? e2 : NEG_SLOPE * e2; dn2 += __expf(e2);
      float e3 = a4.w + adv4.w; e3 = e3 > 0.f ? e3 : NEG_SLOPE * e3; dn3 += __expf(e3);
    }
#pragma unroll
    for (int off = 32; off >= 1; off >>= 1) {
      dn0 += __shfl_xor(dn0, off, 64);
      dn1 += __shfl_xor(dn1, off, 64);
      dn2 += __shfl_xor(dn2, off, 64);
      dn3 += __shfl_xor(dn3, off, 64);
    }
    float adm = myhead == 0 ? adv4.x : myhead == 1 ? adv4.y : myhead == 2 ? adv4.z : adv4.w;
    float invdn = 1.f / (myhead == 0 ? dn0 : myhead == 1 ? dn1 : myhead == 2 ? dn2 : dn3);
    invdn *= inv_deg;
    for (int i = beg; i < end; ++i) {
      int s = col_src[i];
      float e = as_[(size_t)s * 4 + myhead] + adm;
      e = (e > 0.f) ? e : NEG_SLOPE * e;
      float w = __expf(e) * invdn;
      fma_h4(hl + (size_t)s * 256, w, facc);
    }
  }

  float* orow = out + (size_t)node * 256 + lane * 4;
#pragma unroll
  for (int p = 0; p < 4; ++p) {
    float v = facc[p] + bias[lane * 4 + p];
    if (RELU) v = fmaxf(v, 0.f);
    orow[p] = v;
  }
}

// --------------------------- aggregation, H=1 (layer 2): one wave per node
template <bool RELU>
__global__ void aggregate1_kernel(const __half* __restrict__ h16,
                                  const float* __restrict__ as_,
                                  const float* __restrict__ ad_,
                                  const int* __restrict__ row_ptr,
                                  const int* __restrict__ col_src,
                                  const float* __restrict__ bias,
                                  float* __restrict__ out, int N) {
  int lane = threadIdx.x & 63;
  int node = (blockIdx.x * blockDim.x + threadIdx.x) >> 6;
  if (node >= N) return;
  int beg = row_ptr[node], end = row_ptr[node + 1];
  int deg = end - beg;
  float inv_deg = 1.f / (float)deg;
  float adv = ad_[node];
  const __half* hb = h16 + lane;
  float facc = 0.f;

  if (deg <= 64) {
    float q = 0.f; int s_w = 0;
    if (lane < deg) {
      s_w = col_src[beg + lane];
      float e = as_[s_w] + adv;
      e = (e > 0.f) ? e : NEG_SLOPE * e;
      q = __expf(e);
    }
    float dn = q;
#pragma unroll
    for (int off = 32; off >= 1; off >>= 1) dn += __shfl_xor(dn, off, 64);
    float qs = q * (1.f / dn) * inv_deg;
    int deg8 = (deg + 7) & ~7;
    for (int i = 0; i < deg8; i += 8) {
      int s0 = __shfl(s_w, i + 0, 64); float w0 = __shfl(qs, i + 0, 64);
      int s1 = __shfl(s_w, i + 1, 64); float w1 = __shfl(qs, i + 1, 64);
      int s2 = __shfl(s_w, i + 2, 64); float w2 = __shfl(qs, i + 2, 64);
      int s3 = __shfl(s_w, i + 3, 64); float w3 = __shfl(qs, i + 3, 64);
      int s4 = __shfl(s_w, i + 4, 64); float w4 = __shfl(qs, i + 4, 64);
      int s5 = __shfl(s_w, i + 5, 64); float w5 = __shfl(qs, i + 5, 64);
      int s6 = __shfl(s_w, i + 6, 64); float w6 = __shfl(qs, i + 6, 64);
      int s7 = __shfl(s_w, i + 7, 64); float w7 = __shfl(qs, i + 7, 64);
      float v0 = __half2float(hb[(size_t)s0 * 64]);
      float v1 = __half2float(hb[(size_t)s1 * 64]);
      float v2 = __half2float(hb[(size_t)s2 * 64]);
      float v3 = __half2float(hb[(size_t)s3 * 64]);
      float v4 = __half2float(hb[(size_t)s4 * 64]);
      float v5 = __half2float(hb[(size_t)s5 * 64]);
      float v6 = __half2float(hb[(size_t)s6 * 64]);
      float v7 = __half2float(hb[(size_t)s7 * 64]);
      facc += v0 * w0 + v1 * w1 + v2 * w2 + v3 * w3;
      facc += v4 * w4 + v5 * w5 + v6 * w6 + v7 * w7;
    }
  } else {
    float dn = 0.f;
    for (int i = beg + lane; i < end; i += 64) {
      int s = col_src[i];
      float e = as_[s] + adv;
      e = (e > 0.f) ? e : NEG_SLOPE * e;
      dn += __expf(e);
    }
#pragma unroll
    for (int off = 32; off >= 1; off >>= 1) dn += __shfl_xor(dn, off, 64);
    float scale = (1.f / dn) * inv_deg;
    for (int base = beg; base < end; base += 64) {
      int i2 = base + lane;
      float q2 = 0.f; int s2r = 0;
      if (i2 < end) {
        s2r = col_src[i2];
        float e = as_[s2r] + adv;
        e = (e > 0.f) ? e : NEG_SLOPE * e;
        q2 = __expf(e) * scale;
      }
      int cnt = end - base; if (cnt > 64) cnt = 64;
      for (int j = 0; j < cnt; ++j) {
        int s = __shfl(s2r, j, 64);
        float w = __shfl(q2, j, 64);
        facc += __half2float(hb[(size_t)s * 64]) * w;
      }
    }
  }

  float vout = facc + bias[lane];
  if (RELU) vout = fmaxf(vout, 0.f);
  out[(size_t)node * 64 + lane] = vout;
}

// ---------------------------------------------------------------- launcher
extern "C" void kernel_launch(void* const* d_in, const int* in_sizes, int n_in,
                              void* d_out, int out_size, void* d_ws, size_t ws_size,
                              hipStream_t stream) {
  const float* x   = (const float*)d_in[0];
  const int*   ei  = (const int*)d_in[1];
  const float* W0  = (const float*)d_in[2];
  const float* a0s = (const float*)d_in[3];
  const float* a0d = (const float*)d_in[4];
  const float* b0  = (const float*)d_in[5];
  const float* W1  = (const float*)d_in[6];
  const float* a1s = (const float*)d_in[7];
  const float* a1d = (const float*)d_in[8];
  const float* b1  = (const float*)d_in[9];
  const float* W2  = (const float*)d_in[10];
  const float* a2s = (const float*)d_in[11];
  const float* a2d = (const float*)d_in[12];
  const float* b2  = (const float*)d_in[13];

  const int IN = 256;
  const int N = in_sizes[0] / IN;       // 50000
  const int E = in_sizes[1] / 2;        // 600000
  const int Etot = E + N;
  const int nb = (N + 1023) / 1024;     // scan tiles

  char* ws = (char*)d_ws;
  size_t off = 0;
  auto alloc = [&](size_t bytes) {
    void* p = ws + off;
    off += (bytes + 255) & ~(size_t)255;
    return p;
  };
  float*  A       = (float*)alloc((size_t)N * 256 * 4);
  float*  Bbuf    = (float*)alloc((size_t)N * 256 * 4);
  __half* A16     = (__half*)alloc((size_t)N * 256 * 2);
  float*  as_buf  = (float*)alloc((size_t)N * 4 * 4);
  float*  ad_buf  = (float*)alloc((size_t)N * 4 * 4);
  int*    row_ptr = (int*)alloc((size_t)(N + 1) * 4);
  int*    cursor  = (int*)alloc((size_t)N * 4);
  int*    cnt     = (int*)alloc((size_t)N * 4);
  int*    col_src = (int*)alloc((size_t)Etot * 4);
  int*    locex   = (int*)alloc((size_t)N * 4);
  int*    blk_sum = (int*)alloc((size_t)nb * 4);
  int*    blk_off = (int*)alloc((size_t)nb * 4);

  // ---- CSR build ----
  zero_int_kernel<<<(N + 255) / 256, 256, 0, stream>>>(cnt, N);
  count_kernel<<<(Etot + 255) / 256, 256, 0, stream>>>(ei, E, N, cnt);
  scanA_kernel<<<nb, 256, 0, stream>>>(cnt, locex, blk_sum, N);
  scanB_kernel<<<1, 64, 0, stream>>>(blk_sum, blk_off, row_ptr, nb, N);
  scanC_kernel<<<(N + 255) / 256, 256, 0, stream>>>(locex, blk_off, row_ptr, cursor, N);
  fill_kernel<<<(Etot + 255) / 256, 256, 0, stream>>>(ei, E, N, cursor, col_src);

  dim3 g0(256 / 128, (N + 127) / 128);  // 2 x 391
  dim3 g2(64 / 64, (N + 127) / 128);    // 1 x 391
  int node_blocks = (N + 3) / 4;        // 4 waves/block, 1 wave/node

  // ---- layer 0 ----
  mfma_gemm<128><<<g0, 256, 0, stream>>>(x, W0, A, A16, N, 256, 256);
  alpha_kernel<4, 64><<<node_blocks, 256, 0, stream>>>(A, a0s, a0d, as_buf, ad_buf, N);
  aggregate4_kernel<true><<<node_blocks, 256, 0, stream>>>(
      A16, as_buf, ad_buf, row_ptr, col_src, b0, Bbuf, N);

  // ---- layer 1 ----
  mfma_gemm<128><<<g0, 256, 0, stream>>>(Bbuf, W1, A, A16, N, 256, 256);
  alpha_kernel<4, 64><<<node_blocks, 256, 0, stream>>>(A, a1s, a1d, as_buf, ad_buf, N);
  aggregate4_kernel<true><<<node_blocks, 256, 0, stream>>>(
      A16, as_buf, ad_buf, row_ptr, col_src, b1, Bbuf, N);

  // ---- layer 2 (H=1, ld=64) ----
  mfma_gemm<64><<<g2, 256, 0, stream>>>(Bbuf, W2, A, A16, N, 64, 256);
  alpha_kernel<1, 64><<<node_blocks, 256, 0, stream>>>(A, a2s, a2d, as_buf, ad_buf, N);
  aggregate1_kernel<false><<<node_blocks, 256, 0, stream>>>(
      A16, as_buf, ad_buf, row_ptr, col_src, b2, (float*)d_out, N);
}